// Round 4
// baseline (35124.963 us; speedup 1.0000x reference)
//
#include <hip/hip_runtime.h>
#include <cstdint>
#include <cstddef>

typedef unsigned short ushort_t;
typedef __attribute__((ext_vector_type(8))) short short8;
typedef __attribute__((ext_vector_type(4))) float floatx4;

#define SS 128
#define BB 64
#define EE 1024
#define HH 1024
#define OO 135
#define WLW 64
#define PLP 32
#define TT 100
#define KP 160    // padded pose K (135 -> 160)
#define KC 2272   // combined K: 1024 (h) + 1024 (esum) + 224 (wsum)
#define NOP 144   // padded pose out dim
#define NWG 64    // persistent grid size (<< 256 CUs -> co-resident)

static __device__ __forceinline__ float bf2f(ushort_t u) {
    union { unsigned int i; float f; } v; v.i = ((unsigned int)u) << 16; return v.f;
}
static __device__ __forceinline__ ushort_t f2bf(float f) {
    union { float f; unsigned int i; } v; v.f = f;
    unsigned int x = v.i;
    x += 0x7fffu + ((x >> 16) & 1u);   // RNE
    return (ushort_t)(x >> 16);
}
// flag-aware input load: isbf=1 -> bf16 element, isbf=0 -> fp32 element.
static __device__ __forceinline__ float ldf(const void* p, long i, unsigned isbf) {
    if (isbf) return bf2f(((const ushort_t*)p)[i]);
    return ((const float*)p)[i];
}
static __device__ __forceinline__ short8 ldfrag(const ushort_t* p) {
    return *reinterpret_cast<const short8*>(p);
}
static __device__ __forceinline__ floatx4 mfma(short8 a, short8 b, floatx4 c) {
    return __builtin_amdgcn_mfma_f32_16x16x32_bf16(a, b, c, 0, 0, 0);
}
static __device__ __forceinline__ float sigmoidf(float x) {
    x = fminf(fmaxf(x, -30.f), 30.f);
    return 1.f / (1.f + __expf(-x));
}
static __device__ __forceinline__ float tanh_f(float x) {
    x = fminf(fmaxf(x, -15.f), 15.f);
    float e = __expf(2.f * x);
    return (e - 1.f) / (e + 1.f);
}
static __device__ __forceinline__ void store_hl(ushort_t* hi_p, ushort_t* lo_p, float v) {
    ushort_t hi = f2bf(v);
    *hi_p = hi;
    *lo_p = f2bf(v - bf2f(hi));
}

// device-wide generation barrier (all NWG wgs co-resident)
static __device__ __forceinline__ void gbar(unsigned* bar, unsigned* gen) {
    __syncthreads();
    if (threadIdx.x == 0) {
        unsigned g = __hip_atomic_load(gen, __ATOMIC_RELAXED, __HIP_MEMORY_SCOPE_AGENT);
        __threadfence();   // publish this wg's writes device-wide
        unsigned a = __hip_atomic_fetch_add(bar, 1u, __ATOMIC_ACQ_REL, __HIP_MEMORY_SCOPE_AGENT);
        if (a == NWG - 1u) {
            __hip_atomic_store(bar, 0u, __ATOMIC_RELAXED, __HIP_MEMORY_SCOPE_AGENT);
            __hip_atomic_store(gen, g + 1u, __ATOMIC_RELEASE, __HIP_MEMORY_SCOPE_AGENT);
        } else {
            unsigned c;
            do {
                __builtin_amdgcn_s_sleep(1);
                c = __hip_atomic_load(gen, __ATOMIC_ACQUIRE, __HIP_MEMORY_SCOPE_AGENT);
            } while (c == g);
        }
        __threadfence();   // invalidate stale caches before reading others' data
    }
    __syncthreads();
}

// ---------------- dtype detect + barrier init ----------------
__global__ void k_detect(const unsigned* __restrict__ enc, unsigned* __restrict__ flag)
{
    __shared__ int cnt;
    if (threadIdx.x == 0) cnt = 0;
    __syncthreads();
    unsigned w = enc[threadIdx.x];
    unsigned ef = (w >> 7) & 0xFFu;      // exponent field of low half viewed as bf16
    if (ef >= 0x70u && ef <= 0x81u) atomicAdd(&cnt, 1);
    __syncthreads();
    if (threadIdx.x == 0) {
        flag[0] = (cnt >= 200) ? 1u : 0u;
        flag[1] = 0u;   // barrier arrival counter
        flag[2] = 0u;   // barrier generation
    }
}

// ---------------- prep: pack/pad/transpose/convert inputs ----------------
__global__ void k_prep(const void* __restrict__ eh, const void* __restrict__ Watt,
                       const void* __restrict__ Wwatt, const void* __restrict__ Wih,
                       const void* __restrict__ Wout, const void* __restrict__ pp,
                       const void* __restrict__ Whh, const void* __restrict__ Wed,
                       const void* __restrict__ enc, const void* __restrict__ words,
                       ushort_t* __restrict__ ehcat, ushort_t* __restrict__ wattT,
                       ushort_t* __restrict__ wwattT, ushort_t* __restrict__ wih_p,
                       ushort_t* __restrict__ wout_p, ushort_t* __restrict__ pp_pad,
                       ushort_t* __restrict__ pose_pad, ushort_t* __restrict__ Wcomb,
                       ushort_t* __restrict__ whh_bf, ushort_t* __restrict__ wed_bf,
                       ushort_t* __restrict__ encbf, ushort_t* __restrict__ wordsbf,
                       const unsigned* __restrict__ flag)
{
    unsigned isbf = flag[0];
    long idx = (long)blockIdx.x * 256 + threadIdx.x;
    const long n1 = BB * EE;             // 65536
    const long n2 = (long)HH * EE;       // 1048576 wattT
    const long n3 = (long)256 * HH;      // 262144  wwattT
    const long n4 = (long)3 * HH * KP;   // 491520  wih_p
    const long n5 = (long)NOP * 3 * HH;  // 442368  wout_p
    const long n6 = (long)PLP * BB * KP; // 327680  pp_pad
    const long n7 = (long)BB * KP;       // 10240   pose_pad
    const long n8 = (long)NOP * 1024;    // 147456  Wcomb cols 0..1023
    const long n9 = (long)3 * HH * HH;   // 3145728 whh_bf
    const long n10 = (long)HH * EE;      // 1048576 wed_bf
    const long n11 = (long)SS * BB * EE; // 8388608 encbf
    const long n12 = (long)WLW * BB * 200; // 819200 wordsbf
    if (idx < n1) {
        int b = (int)(idx >> 10), r = (int)(idx & 1023);
        int c = r >> 9, jj = r & 511;
        ehcat[idx] = f2bf(ldf(eh, (long)(c * BB + b) * 512 + jj, isbf));
        return;
    }
    idx -= n1;
    if (idx < n2) {    // wattT[e][j] = Watt[j][e]
        long e = idx >> 10, j = idx & 1023;
        wattT[idx] = f2bf(ldf(Watt, j * 1024 + e, isbf)); return;
    }
    idx -= n2;
    if (idx < n3) {    // wwattT[e][j] = (e<200) ? Wwatt[j][e] : 0
        long e = idx >> 10, j = idx & 1023;
        wwattT[idx] = (e < 200) ? f2bf(ldf(Wwatt, j * 200 + e, isbf)) : (ushort_t)0; return;
    }
    idx -= n3;
    if (idx < n4) {
        long row = idx / KP, k = idx % KP;
        wih_p[idx] = (k < OO) ? f2bf(ldf(Wih, row * OO + k, isbf)) : (ushort_t)0; return;
    }
    idx -= n4;
    if (idx < n5) {
        long row = idx / (3 * HH), k = idx % (3 * HH);
        wout_p[idx] = (row < OO) ? f2bf(ldf(Wout, row * (3 * HH) + k, isbf)) : (ushort_t)0; return;
    }
    idx -= n5;
    if (idx < n6) {
        long t = idx / (BB * KP); long rem = idx % (BB * KP);
        long b = rem / KP, k = rem % KP;
        pp_pad[idx] = (k < OO) ? f2bf(ldf(pp, (t * BB + b) * OO + k, isbf)) : (ushort_t)0; return;
    }
    idx -= n6;
    if (idx < n7) { pose_pad[idx] = 0; return; }
    idx -= n7;
    if (idx < n8) {    // Wcomb[o][j] = W_out[o][j] for j<1024 (rows >= OO zero)
        long o = idx >> 10, j = idx & 1023;
        Wcomb[o * KC + j] = (o < OO) ? f2bf(ldf(Wout, o * (3 * HH) + j, isbf)) : (ushort_t)0; return;
    }
    idx -= n8;
    if (idx < n9) { whh_bf[idx] = f2bf(ldf(Whh, idx, isbf)); return; }
    idx -= n9;
    if (idx < n10) { wed_bf[idx] = f2bf(ldf(Wed, idx, isbf)); return; }
    idx -= n10;
    if (idx < n11) { encbf[idx] = f2bf(ldf(enc, idx, isbf)); return; }
    idx -= n11;
    if (idx < n12) { wordsbf[idx] = f2bf(ldf(words, idx, isbf)); return; }
}

// ---------------- generic MFMA GEMM (one-time uses) ----------------
__global__ void __launch_bounds__(256) k_gemm(
    const ushort_t* __restrict__ A, const ushort_t* __restrict__ Alo, int lda,
    const ushort_t* __restrict__ Bw, int ldb,
    const void* __restrict__ biasRaw,
    float* __restrict__ outF, ushort_t* __restrict__ outB,
    ushort_t* __restrict__ outHi, ushort_t* __restrict__ outLo,
    int ldo, int M, int N, int K, int ncap, const unsigned* __restrict__ flag)
{
    unsigned isbf = flag[0];
    int lane = threadIdx.x & 63;
    int wid = (blockIdx.x << 2) + (threadIdx.x >> 6);
    int ng = N >> 6;
    int mt = wid / ng, g = wid % ng;
    if (mt * 16 >= M) return;
    int col = lane & 15, quad = lane >> 4;
    const ushort_t* ap = A + (size_t)(mt * 16 + col) * lda + quad * 8;
    const ushort_t* alp = Alo ? (Alo + (size_t)(mt * 16 + col) * lda + quad * 8) : (const ushort_t*)0;
    const ushort_t* bp = Bw + (size_t)((g << 6) + col) * ldb + quad * 8;
    floatx4 ac0 = {0.f, 0.f, 0.f, 0.f}, ac1 = ac0, ac2 = ac0, ac3 = ac0;
    if (alp) {
        for (int k = 0; k < K; k += 32) {
            short8 a = ldfrag(ap + k), al = ldfrag(alp + k);
            short8 f0 = ldfrag(bp + k);
            short8 f1 = ldfrag(bp + (size_t)16 * ldb + k);
            short8 f2 = ldfrag(bp + (size_t)32 * ldb + k);
            short8 f3 = ldfrag(bp + (size_t)48 * ldb + k);
            ac0 = mfma(a, f0, ac0); ac0 = mfma(al, f0, ac0);
            ac1 = mfma(a, f1, ac1); ac1 = mfma(al, f1, ac1);
            ac2 = mfma(a, f2, ac2); ac2 = mfma(al, f2, ac2);
            ac3 = mfma(a, f3, ac3); ac3 = mfma(al, f3, ac3);
        }
    } else {
        for (int k = 0; k < K; k += 32) {
            short8 a = ldfrag(ap + k);
            ac0 = mfma(a, ldfrag(bp + k), ac0);
            ac1 = mfma(a, ldfrag(bp + (size_t)16 * ldb + k), ac1);
            ac2 = mfma(a, ldfrag(bp + (size_t)32 * ldb + k), ac2);
            ac3 = mfma(a, ldfrag(bp + (size_t)48 * ldb + k), ac3);
        }
    }
    int m0 = mt * 16 + quad * 4;
    #pragma unroll
    for (int tIdx = 0; tIdx < 4; ++tIdx) {
        floatx4 ac = (tIdx == 0) ? ac0 : (tIdx == 1) ? ac1 : (tIdx == 2) ? ac2 : ac3;
        int n = (g << 6) + tIdx * 16 + col;
        if (n >= ncap) continue;
        float bv = biasRaw ? ldf(biasRaw, n, isbf) : 0.f;
        #pragma unroll
        for (int r = 0; r < 4; ++r) {
            float v = ac[r] + bv;
            size_t o = (size_t)(m0 + r) * ldo + n;
            if (outF) outF[o] = v;
            if (outB) outB[o] = f2bf(v);
            if (outHi) {
                ushort_t hi = f2bf(v);
                outHi[o] = hi;
                outLo[o] = f2bf(v - bf2f(hi));
            }
        }
    }
}

// ---------------- bcomb = b_out + Wout2 @ b_att + Wout3 @ b_watt ----------------
__global__ void k_bcomb(const ushort_t* __restrict__ wout_p, const void* __restrict__ b_out,
                        const void* __restrict__ b_att, const void* __restrict__ b_watt,
                        float* __restrict__ bcomb, const unsigned* __restrict__ flag)
{
    unsigned isbf = flag[0];
    int o = threadIdx.x;
    if (o >= NOP) return;
    float s = (o < OO) ? ldf(b_out, o, isbf) : 0.f;
    const ushort_t* r2 = wout_p + (size_t)o * (3 * HH) + 1024;
    const ushort_t* r3 = wout_p + (size_t)o * (3 * HH) + 2048;
    for (int j = 0; j < HH; ++j) {
        s += bf2f(r2[j]) * ldf(b_att, j, isbf);
        s += bf2f(r3[j]) * ldf(b_watt, j, isbf);
    }
    bcomb[o] = s;
}

// ---------------- persistent decoder: all 132 steps, 4 phases/step ----------------
__global__ void __launch_bounds__(256, 1) k_persist(
    const ushort_t* __restrict__ encbf, const ushort_t* __restrict__ wordsbf,
    const ushort_t* __restrict__ wattT,   // 1280 rows x 1024 (wwattT contiguous)
    const ushort_t* __restrict__ whh_bf, const ushort_t* __restrict__ wih_p,
    const void* __restrict__ b_ih, const void* __restrict__ b_hh,
    const ushort_t* __restrict__ Wcomb, const float* __restrict__ bcomb,
    const ushort_t* __restrict__ pp_pad, ushort_t* __restrict__ pose_pad,
    float* hFa, float* hFb, ushort_t* hhia, ushort_t* hhib,
    ushort_t* hloa, ushort_t* hlob,
    float* __restrict__ gcat, ushort_t* __restrict__ cxh, ushort_t* __restrict__ cxl,
    void* __restrict__ out, unsigned* flagbar)
{
    const int tid = threadIdx.x;
    const int lane = tid & 63, wv = tid >> 6;
    const int wg = blockIdx.x;
    const int col = lane & 15, quad = lane >> 4;
    unsigned isbf = flagbar[0];
    unsigned* bar = flagbar + 1;
    unsigned* gen = flagbar + 2;

    float* hFs = hFa; float* hFd = hFb;
    ushort_t* hhis = hhia; ushort_t* hhid = hhib;
    ushort_t* hlos = hloa; ushort_t* hlod = hlob;

    __shared__ float gs[1280];
    __shared__ float sc[192];
    __shared__ float wts[192];

    // GRU bias scalars for this wg's j-slice (constant across steps)
    const int j = wg * 16 + col;
    const float bir = ldf(b_ih, j, isbf)          + ldf(b_hh, j, isbf);
    const float biz = ldf(b_ih, HH + j, isbf)     + ldf(b_hh, HH + j, isbf);
    const float bin = ldf(b_ih, 2 * HH + j, isbf);
    const float bhn = ldf(b_hh, 2 * HH + j, isbf);

    for (int t = 0; t < PLP + TT; ++t) {
        const bool dec = (t >= PLP);
        const ushort_t* poseA = (t < PLP)  ? (pp_pad + (size_t)t * BB * KP)
                              : (t == PLP) ? (pp_pad + (size_t)(PLP - 1) * BB * KP)
                                           : pose_pad;
        // ======== phase 1: GRU (64 wgs, wg = j-tile) ========
        {
            const ushort_t* ah = hhis + (size_t)(wv * 16 + col) * HH + quad * 8;
            const ushort_t* al = hlos + (size_t)(wv * 16 + col) * HH + quad * 8;
            const ushort_t* w0 = whh_bf + (size_t)(wg * 16 + col) * HH + quad * 8;
            const ushort_t* w1 = w0 + (size_t)HH * HH;
            const ushort_t* w2 = w0 + (size_t)2 * HH * HH;
            floatx4 aR = {0.f, 0.f, 0.f, 0.f}, aZ = aR, aNi = aR, aNh = aR;
            for (int k = 0; k < HH; k += 32) {
                short8 f0 = ldfrag(w0 + k), f1 = ldfrag(w1 + k), f2 = ldfrag(w2 + k);
                short8 xh = ldfrag(ah + k), xl = ldfrag(al + k);
                aR = mfma(xh, f0, aR);   aR = mfma(xl, f0, aR);
                aZ = mfma(xh, f1, aZ);   aZ = mfma(xl, f1, aZ);
                aNh = mfma(xh, f2, aNh); aNh = mfma(xl, f2, aNh);
            }
            const ushort_t* ap = poseA + (size_t)(wv * 16 + col) * KP + quad * 8;
            const ushort_t* c0 = wih_p + (size_t)(wg * 16 + col) * KP + quad * 8;
            const ushort_t* c1 = c0 + (size_t)HH * KP;
            const ushort_t* c2 = c0 + (size_t)2 * HH * KP;
            for (int k = 0; k < KP; k += 32) {
                short8 xp = ldfrag(ap + k);
                aR = mfma(xp, ldfrag(c0 + k), aR);
                aZ = mfma(xp, ldfrag(c1 + k), aZ);
                aNi = mfma(xp, ldfrag(c2 + k), aNi);
            }
            #pragma unroll
            for (int r = 0; r < 4; ++r) {
                int b = wv * 16 + quad * 4 + r;
                float hold = hFs[(size_t)b * HH + j];
                float rg = sigmoidf(aR[r] + bir);
                float zg = sigmoidf(aZ[r] + biz);
                float ng = tanh_f(aNi[r] + bin + rg * (aNh[r] + bhn));
                float hn = (1.f - zg) * ng + zg * hold;
                hFd[(size_t)b * HH + j] = hn;
                ushort_t hi = f2bf(hn);
                ushort_t lo = f2bf(hn - bf2f(hi));
                hhid[(size_t)b * HH + j] = hi;
                hlod[(size_t)b * HH + j] = lo;
                if (dec) { cxh[(size_t)b * KC + j] = hi; cxl[(size_t)b * KC + j] = lo; }
            }
        }
        { float* tf = hFs; hFs = hFd; hFd = tf; }
        { ushort_t* tp = hhis; hhis = hhid; hhid = tp;
          tp = hlos; hlos = hlod; hlod = tp; }
        gbar(bar, gen);
        if (!dec) continue;

        // ======== phase 2: gcat = h @ [wattT|wwattT]^T (80 waves) ========
        {
            int wid = wg * 4 + wv;
            if (wid < 80) {
                int mt = wid / 20, g = wid % 20;
                const ushort_t* ap = hhis + (size_t)(mt * 16 + col) * HH + quad * 8;
                const ushort_t* alp = hlos + (size_t)(mt * 16 + col) * HH + quad * 8;
                const ushort_t* bp = wattT + (size_t)((g << 6) + col) * HH + quad * 8;
                floatx4 a0 = {0.f, 0.f, 0.f, 0.f}, a1 = a0, a2 = a0, a3 = a0;
                for (int k = 0; k < HH; k += 32) {
                    short8 xh = ldfrag(ap + k), xl = ldfrag(alp + k);
                    short8 f0 = ldfrag(bp + k);
                    short8 f1 = ldfrag(bp + (size_t)16 * HH + k);
                    short8 f2 = ldfrag(bp + (size_t)32 * HH + k);
                    short8 f3 = ldfrag(bp + (size_t)48 * HH + k);
                    a0 = mfma(xh, f0, a0); a0 = mfma(xl, f0, a0);
                    a1 = mfma(xh, f1, a1); a1 = mfma(xl, f1, a1);
                    a2 = mfma(xh, f2, a2); a2 = mfma(xl, f2, a2);
                    a3 = mfma(xh, f3, a3); a3 = mfma(xl, f3, a3);
                }
                int m0 = mt * 16 + quad * 4;
                #pragma unroll
                for (int ti2 = 0; ti2 < 4; ++ti2) {
                    floatx4 ac = (ti2 == 0) ? a0 : (ti2 == 1) ? a1 : (ti2 == 2) ? a2 : a3;
                    int n = (g << 6) + ti2 * 16 + col;
                    #pragma unroll
                    for (int r = 0; r < 4; ++r)
                        gcat[(size_t)(m0 + r) * 1280 + n] = ac[r];
                }
            }
        }
        gbar(bar, gen);

        // ======== phase 3: scores + softmax + esum/wsum (wg = batch) ========
        {
            const int b = wg;
            #pragma unroll
            for (int i = 0; i < 5; ++i) gs[tid + 256 * i] = gcat[(size_t)b * 1280 + tid + 256 * i];
            __syncthreads();
            for (int idx = wv; idx < 192; idx += 4) {
                float s = 0.f;
                if (idx < 128) {
                    const ushort_t* rp = encbf + ((size_t)(idx * BB + b) << 10);
                    #pragma unroll
                    for (int jj = 0; jj < 16; ++jj) {
                        int k = lane + (jj << 6);
                        s += bf2f(rp[k]) * gs[k];
                    }
                } else {
                    const ushort_t* rp = wordsbf + (size_t)((idx - 128) * BB + b) * 200;
                    #pragma unroll
                    for (int jj = 0; jj < 4; ++jj) {
                        int k = lane + (jj << 6);
                        if (k < 200) s += bf2f(rp[k]) * gs[1024 + k];
                    }
                }
                #pragma unroll
                for (int m = 1; m < 64; m <<= 1) s += __shfl_xor(s, m);
                if (lane == 0) sc[idx] = s;
            }
            __syncthreads();
            if (wv == 0) {
                float a = sc[lane], c = sc[lane + 64];
                float mx = fmaxf(a, c);
                #pragma unroll
                for (int m = 1; m < 64; m <<= 1) mx = fmaxf(mx, __shfl_xor(mx, m));
                float e0 = __expf(a - mx), e1 = __expf(c - mx);
                float sm = e0 + e1;
                #pragma unroll
                for (int m = 1; m < 64; m <<= 1) sm += __shfl_xor(sm, m);
                float inv = 1.f / sm;
                wts[lane] = e0 * inv; wts[lane + 64] = e1 * inv;
            } else if (wv == 1) {
                float a = sc[128 + lane];
                float mx = a;
                #pragma unroll
                for (int m = 1; m < 64; m <<= 1) mx = fmaxf(mx, __shfl_xor(mx, m));
                float e0 = __expf(a - mx);
                float sm = e0;
                #pragma unroll
                for (int m = 1; m < 64; m <<= 1) sm += __shfl_xor(sm, m);
                wts[128 + lane] = e0 / sm;
            }
            __syncthreads();
            float a0 = 0.f, a1 = 0.f, a2 = 0.f, a3 = 0.f;
            for (int s = 0; s < SS; ++s) {
                float w = wts[s];
                const ushort_t* rp = encbf + ((size_t)(s * BB + b) << 10) + tid;
                a0 += w * bf2f(rp[0]);   a1 += w * bf2f(rp[256]);
                a2 += w * bf2f(rp[512]); a3 += w * bf2f(rp[768]);
            }
            size_t cb = (size_t)b * KC + 1024;
            store_hl(cxh + cb + tid, cxl + cb + tid, a0);
            store_hl(cxh + cb + tid + 256, cxl + cb + tid + 256, a1);
            store_hl(cxh + cb + tid + 512, cxl + cb + tid + 512, a2);
            store_hl(cxh + cb + tid + 768, cxl + cb + tid + 768, a3);
            if (tid < 224) {
                float s224 = 0.f;
                if (tid < 200) {
                    for (int s = 0; s < WLW; ++s)
                        s224 += wts[128 + s] * bf2f(wordsbf[(size_t)(s * BB + b) * 200 + tid]);
                }
                size_t cw = (size_t)b * KC + 2048 + tid;
                store_hl(cxh + cw, cxl + cw, s224);
            }
        }
        gbar(bar, gen);

        // ======== phase 4: pose = catx @ Wcomb^T + bcomb (36 waves) ========
        {
            int wid = wg * 4 + wv;
            if (wid < 36) {
                int mt = wid / 9, nt = wid % 9;
                const ushort_t* ah = cxh + (size_t)(mt * 16 + col) * KC + quad * 8;
                const ushort_t* al = cxl + (size_t)(mt * 16 + col) * KC + quad * 8;
                const ushort_t* bp = Wcomb + (size_t)(nt * 16 + col) * KC + quad * 8;
                floatx4 ac = {0.f, 0.f, 0.f, 0.f};
                for (int k = 0; k < KC; k += 32) {
                    short8 bf = ldfrag(bp + k);
                    ac = mfma(ldfrag(ah + k), bf, ac);
                    ac = mfma(ldfrag(al + k), bf, ac);
                }
                int o = nt * 16 + col;
                float bv = bcomb[o];
                int td = t - PLP;
                #pragma unroll
                for (int r = 0; r < 4; ++r) {
                    int bidx = mt * 16 + quad * 4 + r;
                    float v = ac[r] + bv;
                    if (o < OO) {
                        size_t oi = ((size_t)td * BB + bidx) * OO + o;
                        if (isbf) ((ushort_t*)out)[oi] = f2bf(v);
                        else      ((float*)out)[oi] = v;
                    }
                    pose_pad[(size_t)bidx * KP + o] = (o < OO) ? f2bf(v) : (ushort_t)0;
                }
            }
        }
        gbar(bar, gen);
    }
}

extern "C" void kernel_launch(void* const* d_in, const int* in_sizes, int n_in,
                              void* d_out, int out_size, void* d_ws, size_t ws_size,
                              hipStream_t stream)
{
    (void)in_sizes; (void)n_in; (void)out_size; (void)ws_size;
    const void* enc_states = d_in[0];
    const void* enc_hidden = d_in[1];
    const void* prev_poses = d_in[2];
    const void* words      = d_in[3];
    // d_in[4] = real_poses_len (fixed 100)
    const void* W_ed  = d_in[5];
    const void* b_ed  = d_in[6];
    const void* W_att = d_in[7];
    const void* b_att = d_in[8];
    const void* W_watt = d_in[9];
    const void* b_watt = d_in[10];
    const void* W_ih  = d_in[11];
    const void* W_hh  = d_in[12];
    const void* b_ih  = d_in[13];
    const void* b_hh  = d_in[14];
    const void* W_out = d_in[15];
    const void* b_out = d_in[16];

    char* base = (char*)d_ws;
    size_t off = 0;
    auto alloc = [&](size_t bytes) -> char* {
        char* p = base + off;
        off = (off + bytes + 255) & ~(size_t)255;
        return p;
    };
    unsigned* flagbar  = (unsigned*)alloc(256);
    ushort_t* ehcat    = (ushort_t*)alloc((size_t)BB * EE * 2);
    ushort_t* wattT    = (ushort_t*)alloc((size_t)HH * EE * 2);       // 2 MB (multiple of 256)
    ushort_t* wwattT   = (ushort_t*)alloc((size_t)256 * HH * 2);      // contiguous after wattT
    ushort_t* wih_p    = (ushort_t*)alloc((size_t)3 * HH * KP * 2);
    ushort_t* wout_p   = (ushort_t*)alloc((size_t)NOP * 3 * HH * 2);
    ushort_t* pp_pad   = (ushort_t*)alloc((size_t)PLP * BB * KP * 2);
    ushort_t* pose_pad = (ushort_t*)alloc((size_t)BB * KP * 2);
    ushort_t* Wcomb    = (ushort_t*)alloc((size_t)NOP * KC * 2);
    float*    bcomb    = (float*)alloc((size_t)NOP * 4);
    ushort_t* whh_bf   = (ushort_t*)alloc((size_t)3 * HH * HH * 2);   // 6.3 MB
    ushort_t* wed_bf   = (ushort_t*)alloc((size_t)HH * EE * 2);       // 2 MB
    float*    hF0      = (float*)alloc((size_t)BB * HH * 4);
    float*    hF1      = (float*)alloc((size_t)BB * HH * 4);
    ushort_t* hhi0     = (ushort_t*)alloc((size_t)BB * HH * 2);
    ushort_t* hhi1     = (ushort_t*)alloc((size_t)BB * HH * 2);
    ushort_t* hlo0     = (ushort_t*)alloc((size_t)BB * HH * 2);
    ushort_t* hlo1     = (ushort_t*)alloc((size_t)BB * HH * 2);
    float*    gcat     = (float*)alloc((size_t)BB * 1280 * 4);
    ushort_t* cxh      = (ushort_t*)alloc((size_t)BB * KC * 2);
    ushort_t* cxl      = (ushort_t*)alloc((size_t)BB * KC * 2);
    ushort_t* encbf    = (ushort_t*)alloc((size_t)SS * BB * EE * 2);  // 16.8 MB
    ushort_t* wordsbf  = (ushort_t*)alloc((size_t)WLW * BB * 200 * 2);// 1.6 MB
    // total ~35.5 MB

    k_detect<<<1, 256, 0, stream>>>((const unsigned*)enc_states, flagbar);

    k_prep<<<63272, 256, 0, stream>>>(enc_hidden, W_att, W_watt, W_ih, W_out, prev_poses,
                                      W_hh, W_ed, enc_states, words,
                                      ehcat, wattT, wwattT, wih_p, wout_p, pp_pad, pose_pad,
                                      Wcomb, whh_bf, wed_bf, encbf, wordsbf, flagbar);

    // h0 = ehcat @ W_ed^T + b_ed    (M=64, N=1024, K=1024)
    k_gemm<<<16, 256, 0, stream>>>(ehcat, nullptr, EE, wed_bf, EE, b_ed,
                                   hF0, nullptr, hhi0, hlo0, HH, BB, HH, EE, HH, flagbar);
    // Wcomb cols 1024..2047 = wout2 @ wattT^T   (M=144, N=1024, K=1024)
    k_gemm<<<36, 256, 0, stream>>>(wout_p + 1024, nullptr, 3 * HH, wattT, HH, nullptr,
                                   nullptr, Wcomb + 1024, nullptr, nullptr, KC, NOP, HH, HH, HH, flagbar);
    // Wcomb cols 2048..2271 = wout3 @ wwattT^T  (M=144, N=256 capped 224, K=1024)
    k_gemm<<<9, 256, 0, stream>>>(wout_p + 2048, nullptr, 3 * HH, wwattT, HH, nullptr,
                                  nullptr, Wcomb + 2048, nullptr, nullptr, KC, NOP, 256, HH, 224, flagbar);
    k_bcomb<<<1, 256, 0, stream>>>(wout_p, b_out, b_att, b_watt, bcomb, flagbar);

    k_persist<<<NWG, 256, 0, stream>>>(encbf, wordsbf, wattT, whh_bf, wih_p,
                                       b_ih, b_hh, Wcomb, bcomb, pp_pad, pose_pad,
                                       hF0, hF1, hhi0, hhi1, hlo0, hlo1,
                                       gcat, cxh, cxl, d_out, flagbar);
}

// Round 5
// 28116.687 us; speedup vs baseline: 1.2493x; 1.2493x over previous
//
#include <hip/hip_runtime.h>
#include <cstdint>
#include <cstddef>

typedef unsigned short ushort_t;
typedef __attribute__((ext_vector_type(8))) short short8;
typedef __attribute__((ext_vector_type(4))) float floatx4;

#define SS 128
#define BB 64
#define EE 1024
#define HH 1024
#define OO 135
#define WLW 64
#define PLP 32
#define TT 100
#define KP 160    // padded pose K (135 -> 160)
#define KC 2272   // combined K: 1024 (h) + 1024 (esum) + 224 (wsum)
#define NOP 144   // padded pose out dim
#define NWG 64    // persistent grid size (co-resident)

// LDS layout (dynamic, 131072 B total)
#define WHH_PITCH 1032           // shorts; bank stride 516%32=4 -> 2-way (free)
#define WIH_PITCH 168            // shorts; bank stride 84%32=20 -> 2-way (free)
#define LDS_WHH   0              // 48 rows * 1032 * 2B = 99072
#define LDS_WIH   99072          // 48 rows * 168 * 2B  = 16128
#define LDS_GS    115200         // 1280 f32 = 5120
#define LDS_CX    120320         // 2304 f32 = 9216
#define LDS_SC    129536         // 192 f32
#define LDS_WTS   130304         // 192 f32  -> end 131072

static __device__ __forceinline__ float bf2f(ushort_t u) {
    union { unsigned int i; float f; } v; v.i = ((unsigned int)u) << 16; return v.f;
}
static __device__ __forceinline__ ushort_t f2bf(float f) {
    union { float f; unsigned int i; } v; v.f = f;
    unsigned int x = v.i;
    x += 0x7fffu + ((x >> 16) & 1u);   // RNE
    return (ushort_t)(x >> 16);
}
static __device__ __forceinline__ float ldf(const void* p, long i, unsigned isbf) {
    if (isbf) return bf2f(((const ushort_t*)p)[i]);
    return ((const float*)p)[i];
}
static __device__ __forceinline__ short8 ldfrag(const ushort_t* p) {
    return *reinterpret_cast<const short8*>(p);
}
static __device__ __forceinline__ short8 ldfrag_l(const short* p) {
    return *reinterpret_cast<const short8*>(p);
}
static __device__ __forceinline__ floatx4 mfma(short8 a, short8 b, floatx4 c) {
    return __builtin_amdgcn_mfma_f32_16x16x32_bf16(a, b, c, 0, 0, 0);
}
static __device__ __forceinline__ float sigmoidf(float x) {
    x = fminf(fmaxf(x, -30.f), 30.f);
    return 1.f / (1.f + __expf(-x));
}
static __device__ __forceinline__ float tanh_f(float x) {
    x = fminf(fmaxf(x, -15.f), 15.f);
    float e = __expf(2.f * x);
    return (e - 1.f) / (e + 1.f);
}

// device-wide generation barrier: RELAXED spin + exactly one release/acquire fence.
static __device__ __forceinline__ void gbar(unsigned* bar, unsigned* gen) {
    __syncthreads();
    if (threadIdx.x == 0) {
        unsigned g = __hip_atomic_load(gen, __ATOMIC_RELAXED, __HIP_MEMORY_SCOPE_AGENT);
        __builtin_amdgcn_fence(__ATOMIC_RELEASE, "agent");   // publish prior writes (one wb)
        unsigned a = __hip_atomic_fetch_add(bar, 1u, __ATOMIC_RELAXED, __HIP_MEMORY_SCOPE_AGENT);
        if (a == NWG - 1u) {
            __hip_atomic_store(bar, 0u, __ATOMIC_RELAXED, __HIP_MEMORY_SCOPE_AGENT);
            __hip_atomic_store(gen, g + 1u, __ATOMIC_RELAXED, __HIP_MEMORY_SCOPE_AGENT);
        } else {
            unsigned c;
            do {
                __builtin_amdgcn_s_sleep(2);
                c = __hip_atomic_load(gen, __ATOMIC_RELAXED, __HIP_MEMORY_SCOPE_AGENT);
            } while (c == g);
        }
        __builtin_amdgcn_fence(__ATOMIC_ACQUIRE, "agent");   // one inv, after the wait
    }
    __syncthreads();
}

// ---------------- dtype detect + barrier init ----------------
__global__ void k_detect(const unsigned* __restrict__ enc, unsigned* __restrict__ flag)
{
    __shared__ int cnt;
    if (threadIdx.x == 0) cnt = 0;
    __syncthreads();
    unsigned w = enc[threadIdx.x];
    unsigned ef = (w >> 7) & 0xFFu;
    if (ef >= 0x70u && ef <= 0x81u) atomicAdd(&cnt, 1);
    __syncthreads();
    if (threadIdx.x == 0) {
        flag[0] = (cnt >= 200) ? 1u : 0u;
        flag[1] = 0u;   // barrier arrival counter
        flag[2] = 0u;   // barrier generation
    }
}

// ---------------- prep: pack/pad/transpose/convert inputs ----------------
__global__ void k_prep(const void* __restrict__ eh, const void* __restrict__ Watt,
                       const void* __restrict__ Wwatt, const void* __restrict__ Wih,
                       const void* __restrict__ Wout, const void* __restrict__ pp,
                       const void* __restrict__ Whh, const void* __restrict__ Wed,
                       const void* __restrict__ enc, const void* __restrict__ words,
                       ushort_t* __restrict__ ehcat, ushort_t* __restrict__ wattT,
                       ushort_t* __restrict__ wwattT, ushort_t* __restrict__ wih_p,
                       ushort_t* __restrict__ wout_p, ushort_t* __restrict__ pp_pad,
                       ushort_t* __restrict__ pose_pad, ushort_t* __restrict__ Wcomb,
                       ushort_t* __restrict__ whh_bf, ushort_t* __restrict__ wed_bf,
                       ushort_t* __restrict__ encbf, ushort_t* __restrict__ wordsbf,
                       const unsigned* __restrict__ flag)
{
    unsigned isbf = flag[0];
    long idx = (long)blockIdx.x * 256 + threadIdx.x;
    const long n1 = BB * EE;
    const long n2 = (long)HH * EE;
    const long n3 = (long)256 * HH;
    const long n4 = (long)3 * HH * KP;
    const long n5 = (long)NOP * 3 * HH;
    const long n6 = (long)PLP * BB * KP;
    const long n7 = (long)BB * KP;
    const long n8 = (long)NOP * 1024;
    const long n9 = (long)3 * HH * HH;
    const long n10 = (long)HH * EE;
    const long n11 = (long)SS * BB * EE;
    const long n12 = (long)WLW * BB * 200;
    if (idx < n1) {
        int b = (int)(idx >> 10), r = (int)(idx & 1023);
        int c = r >> 9, jj = r & 511;
        ehcat[idx] = f2bf(ldf(eh, (long)(c * BB + b) * 512 + jj, isbf));
        return;
    }
    idx -= n1;
    if (idx < n2) {
        long e = idx >> 10, j = idx & 1023;
        wattT[idx] = f2bf(ldf(Watt, j * 1024 + e, isbf)); return;
    }
    idx -= n2;
    if (idx < n3) {
        long e = idx >> 10, j = idx & 1023;
        wwattT[idx] = (e < 200) ? f2bf(ldf(Wwatt, j * 200 + e, isbf)) : (ushort_t)0; return;
    }
    idx -= n3;
    if (idx < n4) {
        long row = idx / KP, k = idx % KP;
        wih_p[idx] = (k < OO) ? f2bf(ldf(Wih, row * OO + k, isbf)) : (ushort_t)0; return;
    }
    idx -= n4;
    if (idx < n5) {
        long row = idx / (3 * HH), k = idx % (3 * HH);
        wout_p[idx] = (row < OO) ? f2bf(ldf(Wout, row * (3 * HH) + k, isbf)) : (ushort_t)0; return;
    }
    idx -= n5;
    if (idx < n6) {
        long t = idx / (BB * KP); long rem = idx % (BB * KP);
        long b = rem / KP, k = rem % KP;
        pp_pad[idx] = (k < OO) ? f2bf(ldf(pp, (t * BB + b) * OO + k, isbf)) : (ushort_t)0; return;
    }
    idx -= n6;
    if (idx < n7) { pose_pad[idx] = 0; return; }
    idx -= n7;
    if (idx < n8) {
        long o = idx >> 10, j = idx & 1023;
        Wcomb[o * KC + j] = (o < OO) ? f2bf(ldf(Wout, o * (3 * HH) + j, isbf)) : (ushort_t)0; return;
    }
    idx -= n8;
    if (idx < n9) { whh_bf[idx] = f2bf(ldf(Whh, idx, isbf)); return; }
    idx -= n9;
    if (idx < n10) { wed_bf[idx] = f2bf(ldf(Wed, idx, isbf)); return; }
    idx -= n10;
    if (idx < n11) { encbf[idx] = f2bf(ldf(enc, idx, isbf)); return; }
    idx -= n11;
    if (idx < n12) { wordsbf[idx] = f2bf(ldf(words, idx, isbf)); return; }
}

// ---------------- generic MFMA GEMM (one-time uses) ----------------
__global__ void __launch_bounds__(256) k_gemm(
    const ushort_t* __restrict__ A, const ushort_t* __restrict__ Alo, int lda,
    const ushort_t* __restrict__ Bw, int ldb,
    const void* __restrict__ biasRaw,
    float* __restrict__ outF, ushort_t* __restrict__ outB,
    ushort_t* __restrict__ outHi, ushort_t* __restrict__ outLo,
    int ldo, int M, int N, int K, int ncap, const unsigned* __restrict__ flag)
{
    unsigned isbf = flag[0];
    int lane = threadIdx.x & 63;
    int wid = (blockIdx.x << 2) + (threadIdx.x >> 6);
    int ng = N >> 6;
    int mt = wid / ng, g = wid % ng;
    if (mt * 16 >= M) return;
    int col = lane & 15, quad = lane >> 4;
    const ushort_t* ap = A + (size_t)(mt * 16 + col) * lda + quad * 8;
    const ushort_t* alp = Alo ? (Alo + (size_t)(mt * 16 + col) * lda + quad * 8) : (const ushort_t*)0;
    const ushort_t* bp = Bw + (size_t)((g << 6) + col) * ldb + quad * 8;
    floatx4 ac0 = {0.f, 0.f, 0.f, 0.f}, ac1 = ac0, ac2 = ac0, ac3 = ac0;
    if (alp) {
        for (int k = 0; k < K; k += 32) {
            short8 a = ldfrag(ap + k), al = ldfrag(alp + k);
            short8 f0 = ldfrag(bp + k);
            short8 f1 = ldfrag(bp + (size_t)16 * ldb + k);
            short8 f2 = ldfrag(bp + (size_t)32 * ldb + k);
            short8 f3 = ldfrag(bp + (size_t)48 * ldb + k);
            ac0 = mfma(a, f0, ac0); ac0 = mfma(al, f0, ac0);
            ac1 = mfma(a, f1, ac1); ac1 = mfma(al, f1, ac1);
            ac2 = mfma(a, f2, ac2); ac2 = mfma(al, f2, ac2);
            ac3 = mfma(a, f3, ac3); ac3 = mfma(al, f3, ac3);
        }
    } else {
        for (int k = 0; k < K; k += 32) {
            short8 a = ldfrag(ap + k);
            ac0 = mfma(a, ldfrag(bp + k), ac0);
            ac1 = mfma(a, ldfrag(bp + (size_t)16 * ldb + k), ac1);
            ac2 = mfma(a, ldfrag(bp + (size_t)32 * ldb + k), ac2);
            ac3 = mfma(a, ldfrag(bp + (size_t)48 * ldb + k), ac3);
        }
    }
    int m0 = mt * 16 + quad * 4;
    #pragma unroll
    for (int tIdx = 0; tIdx < 4; ++tIdx) {
        floatx4 ac = (tIdx == 0) ? ac0 : (tIdx == 1) ? ac1 : (tIdx == 2) ? ac2 : ac3;
        int n = (g << 6) + tIdx * 16 + col;
        if (n >= ncap) continue;
        float bv = biasRaw ? ldf(biasRaw, n, isbf) : 0.f;
        #pragma unroll
        for (int r = 0; r < 4; ++r) {
            float v = ac[r] + bv;
            size_t o = (size_t)(m0 + r) * ldo + n;
            if (outF) outF[o] = v;
            if (outB) outB[o] = f2bf(v);
            if (outHi) {
                ushort_t hi = f2bf(v);
                outHi[o] = hi;
                outLo[o] = f2bf(v - bf2f(hi));
            }
        }
    }
}

// ---------------- bcomb = b_out + Wout2 @ b_att + Wout3 @ b_watt ----------------
__global__ void k_bcomb(const ushort_t* __restrict__ wout_p, const void* __restrict__ b_out,
                        const void* __restrict__ b_att, const void* __restrict__ b_watt,
                        float* __restrict__ bcomb, const unsigned* __restrict__ flag)
{
    unsigned isbf = flag[0];
    int o = threadIdx.x;
    if (o >= NOP) return;
    float s = (o < OO) ? ldf(b_out, o, isbf) : 0.f;
    const ushort_t* r2 = wout_p + (size_t)o * (3 * HH) + 1024;
    const ushort_t* r3 = wout_p + (size_t)o * (3 * HH) + 2048;
    for (int j = 0; j < HH; ++j) {
        s += bf2f(r2[j]) * ldf(b_att, j, isbf);
        s += bf2f(r3[j]) * ldf(b_watt, j, isbf);
    }
    bcomb[o] = s;
}

// ---------------- persistent decoder: 132 steps, phases GRU | gcat | attn+pose ----------------
__global__ void __launch_bounds__(256, 1) k_persist(
    const ushort_t* __restrict__ encbf, const ushort_t* __restrict__ wordsbf,
    const ushort_t* __restrict__ wattT,   // 1280 rows x 1024 (wwattT contiguous)
    const ushort_t* __restrict__ whh_bf, const ushort_t* __restrict__ wih_p,
    const void* __restrict__ b_ih, const void* __restrict__ b_hh,
    const ushort_t* __restrict__ Wcomb, const float* __restrict__ bcomb,
    const ushort_t* __restrict__ pp_pad, ushort_t* __restrict__ pose_pad,
    float* hFa, float* hFb, ushort_t* hhia, ushort_t* hhib,
    ushort_t* hloa, ushort_t* hlob,
    float* __restrict__ gcat, void* __restrict__ out, unsigned* flagbar)
{
    extern __shared__ char smem[];
    short* whh_lds = (short*)(smem + LDS_WHH);
    short* wih_lds = (short*)(smem + LDS_WIH);
    float* gs  = (float*)(smem + LDS_GS);
    float* cx  = (float*)(smem + LDS_CX);
    float* sc  = (float*)(smem + LDS_SC);
    float* wts = (float*)(smem + LDS_WTS);

    const int tid = threadIdx.x;
    const int lane = tid & 63, wv = tid >> 6;
    const int wg = blockIdx.x;
    const int col = lane & 15, quad = lane >> 4;
    unsigned isbf = flagbar[0];
    unsigned* bar = flagbar + 1;
    unsigned* gen = flagbar + 2;

    float* hFs = hFa; float* hFd = hFb;
    ushort_t* hhis = hhia; ushort_t* hhid = hhib;
    ushort_t* hlos = hloa; ushort_t* hlod = hlob;

    // ---- stage this wg's GRU weight slice into LDS (once) ----
    for (int s = tid; s < 48 * 128; s += 256) {
        int r = s >> 7;            // 0..47 (gate*16 + row)
        int ko = (s & 127) << 3;   // 0..1016
        int g = r >> 4, rr = r & 15;
        *(short8*)(whh_lds + r * WHH_PITCH + ko) =
            ldfrag(whh_bf + (size_t)g * HH * HH + (size_t)(wg * 16 + rr) * HH + ko);
    }
    for (int s = tid; s < 48 * 20; s += 256) {
        int r = s / 20;
        int ko = (s % 20) << 3;    // 0..152
        int g = r >> 4, rr = r & 15;
        *(short8*)(wih_lds + r * WIH_PITCH + ko) =
            ldfrag(wih_p + (size_t)g * HH * KP + (size_t)(wg * 16 + rr) * KP + ko);
    }
    __syncthreads();

    // GRU bias scalars for this wg's j-slice
    const int j = wg * 16 + col;
    const float bir = ldf(b_ih, j, isbf)          + ldf(b_hh, j, isbf);
    const float biz = ldf(b_ih, HH + j, isbf)     + ldf(b_hh, HH + j, isbf);
    const float bin = ldf(b_ih, 2 * HH + j, isbf);
    const float bhn = ldf(b_hh, 2 * HH + j, isbf);

    for (int t = 0; t < PLP + TT; ++t) {
        const bool dec = (t >= PLP);
        const ushort_t* poseA = (t < PLP)  ? (pp_pad + (size_t)t * BB * KP)
                              : (t == PLP) ? (pp_pad + (size_t)(PLP - 1) * BB * KP)
                                           : pose_pad;
        // ======== phase 1: GRU (wg = j-tile, weights from LDS) ========
        {
            const ushort_t* ah = hhis + (size_t)(wv * 16 + col) * HH + quad * 8;
            const ushort_t* al = hlos + (size_t)(wv * 16 + col) * HH + quad * 8;
            const short* w0 = whh_lds + (size_t)(0  + col) * WHH_PITCH + quad * 8;
            const short* w1 = whh_lds + (size_t)(16 + col) * WHH_PITCH + quad * 8;
            const short* w2 = whh_lds + (size_t)(32 + col) * WHH_PITCH + quad * 8;
            floatx4 aR = {0.f, 0.f, 0.f, 0.f}, aZ = aR, aNi = aR, aNh = aR;
            for (int k = 0; k < HH; k += 32) {
                short8 f0 = ldfrag_l(w0 + k), f1 = ldfrag_l(w1 + k), f2 = ldfrag_l(w2 + k);
                short8 xh = ldfrag(ah + k), xl = ldfrag(al + k);
                aR = mfma(xh, f0, aR);   aR = mfma(xl, f0, aR);
                aZ = mfma(xh, f1, aZ);   aZ = mfma(xl, f1, aZ);
                aNh = mfma(xh, f2, aNh); aNh = mfma(xl, f2, aNh);
            }
            const ushort_t* ap = poseA + (size_t)(wv * 16 + col) * KP + quad * 8;
            const short* c0 = wih_lds + (size_t)(0  + col) * WIH_PITCH + quad * 8;
            const short* c1 = wih_lds + (size_t)(16 + col) * WIH_PITCH + quad * 8;
            const short* c2 = wih_lds + (size_t)(32 + col) * WIH_PITCH + quad * 8;
            for (int k = 0; k < KP; k += 32) {
                short8 xp = ldfrag(ap + k);
                aR = mfma(xp, ldfrag_l(c0 + k), aR);
                aZ = mfma(xp, ldfrag_l(c1 + k), aZ);
                aNi = mfma(xp, ldfrag_l(c2 + k), aNi);
            }
            #pragma unroll
            for (int r = 0; r < 4; ++r) {
                int b = wv * 16 + quad * 4 + r;
                float hold = hFs[(size_t)b * HH + j];
                float rg = sigmoidf(aR[r] + bir);
                float zg = sigmoidf(aZ[r] + biz);
                float ng = tanh_f(aNi[r] + bin + rg * (aNh[r] + bhn));
                float hn = (1.f - zg) * ng + zg * hold;
                hFd[(size_t)b * HH + j] = hn;
                ushort_t hi = f2bf(hn);
                hhid[(size_t)b * HH + j] = hi;
                hlod[(size_t)b * HH + j] = f2bf(hn - bf2f(hi));
            }
        }
        { float* tf = hFs; hFs = hFd; hFd = tf; }
        { ushort_t* tp = hhis; hhis = hhid; hhid = tp;
          tp = hlos; hlos = hlod; hlod = tp; }
        gbar(bar, gen);
        if (!dec) continue;

        // ======== phase 2: gcat = h @ [wattT|wwattT]^T (80 waves) ========
        {
            int wid = wg * 4 + wv;
            if (wid < 80) {
                int mt = wid / 20, g = wid % 20;
                const ushort_t* ap = hhis + (size_t)(mt * 16 + col) * HH + quad * 8;
                const ushort_t* alp = hlos + (size_t)(mt * 16 + col) * HH + quad * 8;
                const ushort_t* bp = wattT + (size_t)((g << 6) + col) * HH + quad * 8;
                floatx4 a0 = {0.f, 0.f, 0.f, 0.f}, a1 = a0, a2 = a0, a3 = a0;
                for (int k = 0; k < HH; k += 32) {
                    short8 xh = ldfrag(ap + k), xl = ldfrag(alp + k);
                    short8 f0 = ldfrag(bp + k);
                    short8 f1 = ldfrag(bp + (size_t)16 * HH + k);
                    short8 f2 = ldfrag(bp + (size_t)32 * HH + k);
                    short8 f3 = ldfrag(bp + (size_t)48 * HH + k);
                    a0 = mfma(xh, f0, a0); a0 = mfma(xl, f0, a0);
                    a1 = mfma(xh, f1, a1); a1 = mfma(xl, f1, a1);
                    a2 = mfma(xh, f2, a2); a2 = mfma(xl, f2, a2);
                    a3 = mfma(xh, f3, a3); a3 = mfma(xl, f3, a3);
                }
                int m0 = mt * 16 + quad * 4;
                #pragma unroll
                for (int ti2 = 0; ti2 < 4; ++ti2) {
                    floatx4 ac = (ti2 == 0) ? a0 : (ti2 == 1) ? a1 : (ti2 == 2) ? a2 : a3;
                    int n = (g << 6) + ti2 * 16 + col;
                    #pragma unroll
                    for (int r = 0; r < 4; ++r)
                        gcat[(size_t)(m0 + r) * 1280 + n] = ac[r];
                }
            }
        }
        gbar(bar, gen);

        // ======== phase 3: scores+softmax+ctx+pose (wg = batch) ========
        {
            const int b = wg;
            #pragma unroll
            for (int i = 0; i < 5; ++i) gs[tid + 256 * i] = gcat[(size_t)b * 1280 + tid + 256 * i];
            #pragma unroll
            for (int i = 0; i < 4; ++i) cx[tid + 256 * i] = hFs[(size_t)b * HH + tid + 256 * i];
            __syncthreads();
            for (int idx = wv; idx < 192; idx += 4) {
                float s = 0.f;
                if (idx < 128) {
                    const ushort_t* rp = encbf + ((size_t)(idx * BB + b) << 10);
                    #pragma unroll
                    for (int jj = 0; jj < 16; ++jj) {
                        int k = lane + (jj << 6);
                        s += bf2f(rp[k]) * gs[k];
                    }
                } else {
                    const ushort_t* rp = wordsbf + (size_t)((idx - 128) * BB + b) * 200;
                    #pragma unroll
                    for (int jj = 0; jj < 4; ++jj) {
                        int k = lane + (jj << 6);
                        if (k < 200) s += bf2f(rp[k]) * gs[1024 + k];
                    }
                }
                #pragma unroll
                for (int m = 1; m < 64; m <<= 1) s += __shfl_xor(s, m);
                if (lane == 0) sc[idx] = s;
            }
            __syncthreads();
            if (wv == 0) {
                float a = sc[lane], c = sc[lane + 64];
                float mx = fmaxf(a, c);
                #pragma unroll
                for (int m = 1; m < 64; m <<= 1) mx = fmaxf(mx, __shfl_xor(mx, m));
                float e0 = __expf(a - mx), e1 = __expf(c - mx);
                float sm = e0 + e1;
                #pragma unroll
                for (int m = 1; m < 64; m <<= 1) sm += __shfl_xor(sm, m);
                float inv = 1.f / sm;
                wts[lane] = e0 * inv; wts[lane + 64] = e1 * inv;
            } else if (wv == 1) {
                float a = sc[128 + lane];
                float mx = a;
                #pragma unroll
                for (int m = 1; m < 64; m <<= 1) mx = fmaxf(mx, __shfl_xor(mx, m));
                float e0 = __expf(a - mx);
                float sm = e0;
                #pragma unroll
                for (int m = 1; m < 64; m <<= 1) sm += __shfl_xor(sm, m);
                wts[128 + lane] = e0 / sm;
            }
            __syncthreads();
            // esum (fp32, straight into LDS cx)
            float a0 = 0.f, a1 = 0.f, a2 = 0.f, a3 = 0.f;
            for (int s = 0; s < SS; ++s) {
                float w = wts[s];
                const ushort_t* rp = encbf + ((size_t)(s * BB + b) << 10) + tid;
                a0 += w * bf2f(rp[0]);   a1 += w * bf2f(rp[256]);
                a2 += w * bf2f(rp[512]); a3 += w * bf2f(rp[768]);
            }
            cx[1024 + tid] = a0; cx[1280 + tid] = a1;
            cx[1536 + tid] = a2; cx[1792 + tid] = a3;
            // wsum -> cx[2048..2303] (zeros beyond 200)
            {
                float s224 = 0.f;
                if (tid < 200) {
                    for (int s = 0; s < WLW; ++s)
                        s224 += wts[128 + s] * bf2f(wordsbf[(size_t)(s * BB + b) * 200 + tid]);
                }
                cx[2048 + tid] = s224;
            }
            __syncthreads();
            // pose[o] = cx . Wcomb[o] + bcomb[o]  (fp32 VALU dot, coalesced)
            int td = t - PLP;
            for (int oo = 0; oo < 36; ++oo) {
                int o = wv * 36 + oo;
                const ushort_t* wr = Wcomb + (size_t)o * KC;
                float s = 0.f;
                for (int i = 0; i < 36; ++i) {
                    int k = lane + (i << 6);
                    float wf = (k < KC) ? bf2f(wr[k]) : 0.f;
                    s += cx[k] * wf;
                }
                #pragma unroll
                for (int m = 1; m < 64; m <<= 1) s += __shfl_xor(s, m);
                if (lane == 0) {
                    float v = s + bcomb[o];
                    if (o < OO) {
                        size_t oi = ((size_t)td * BB + b) * OO + o;
                        if (isbf) ((ushort_t*)out)[oi] = f2bf(v);
                        else      ((float*)out)[oi] = v;
                    }
                    pose_pad[(size_t)b * KP + o] = (o < OO) ? f2bf(v) : (ushort_t)0;
                }
            }
        }
        gbar(bar, gen);
    }
}

extern "C" void kernel_launch(void* const* d_in, const int* in_sizes, int n_in,
                              void* d_out, int out_size, void* d_ws, size_t ws_size,
                              hipStream_t stream)
{
    (void)in_sizes; (void)n_in; (void)out_size; (void)ws_size;
    const void* enc_states = d_in[0];
    const void* enc_hidden = d_in[1];
    const void* prev_poses = d_in[2];
    const void* words      = d_in[3];
    const void* W_ed  = d_in[5];
    const void* b_ed  = d_in[6];
    const void* W_att = d_in[7];
    const void* b_att = d_in[8];
    const void* W_watt = d_in[9];
    const void* b_watt = d_in[10];
    const void* W_ih  = d_in[11];
    const void* W_hh  = d_in[12];
    const void* b_ih  = d_in[13];
    const void* b_hh  = d_in[14];
    const void* W_out = d_in[15];
    const void* b_out = d_in[16];

    char* base = (char*)d_ws;
    size_t off = 0;
    auto alloc = [&](size_t bytes) -> char* {
        char* p = base + off;
        off = (off + bytes + 255) & ~(size_t)255;
        return p;
    };
    unsigned* flagbar  = (unsigned*)alloc(256);
    ushort_t* ehcat    = (ushort_t*)alloc((size_t)BB * EE * 2);
    ushort_t* wattT    = (ushort_t*)alloc((size_t)HH * EE * 2);
    ushort_t* wwattT   = (ushort_t*)alloc((size_t)256 * HH * 2);  // contiguous after wattT
    ushort_t* wih_p    = (ushort_t*)alloc((size_t)3 * HH * KP * 2);
    ushort_t* wout_p   = (ushort_t*)alloc((size_t)NOP * 3 * HH * 2);
    ushort_t* pp_pad   = (ushort_t*)alloc((size_t)PLP * BB * KP * 2);
    ushort_t* pose_pad = (ushort_t*)alloc((size_t)BB * KP * 2);
    ushort_t* Wcomb    = (ushort_t*)alloc((size_t)NOP * KC * 2);
    float*    bcomb    = (float*)alloc((size_t)NOP * 4);
    ushort_t* whh_bf   = (ushort_t*)alloc((size_t)3 * HH * HH * 2);
    ushort_t* wed_bf   = (ushort_t*)alloc((size_t)HH * EE * 2);
    float*    hF0      = (float*)alloc((size_t)BB * HH * 4);
    float*    hF1      = (float*)alloc((size_t)BB * HH * 4);
    ushort_t* hhi0     = (ushort_t*)alloc((size_t)BB * HH * 2);
    ushort_t* hhi1     = (ushort_t*)alloc((size_t)BB * HH * 2);
    ushort_t* hlo0     = (ushort_t*)alloc((size_t)BB * HH * 2);
    ushort_t* hlo1     = (ushort_t*)alloc((size_t)BB * HH * 2);
    float*    gcat     = (float*)alloc((size_t)BB * 1280 * 4);
    ushort_t* encbf    = (ushort_t*)alloc((size_t)SS * BB * EE * 2);
    ushort_t* wordsbf  = (ushort_t*)alloc((size_t)WLW * BB * 200 * 2);

    k_detect<<<1, 256, 0, stream>>>((const unsigned*)enc_states, flagbar);

    k_prep<<<63272, 256, 0, stream>>>(enc_hidden, W_att, W_watt, W_ih, W_out, prev_poses,
                                      W_hh, W_ed, enc_states, words,
                                      ehcat, wattT, wwattT, wih_p, wout_p, pp_pad, pose_pad,
                                      Wcomb, whh_bf, wed_bf, encbf, wordsbf, flagbar);

    k_gemm<<<16, 256, 0, stream>>>(ehcat, nullptr, EE, wed_bf, EE, b_ed,
                                   hF0, nullptr, hhi0, hlo0, HH, BB, HH, EE, HH, flagbar);
    k_gemm<<<36, 256, 0, stream>>>(wout_p + 1024, nullptr, 3 * HH, wattT, HH, nullptr,
                                   nullptr, Wcomb + 1024, nullptr, nullptr, KC, NOP, HH, HH, HH, flagbar);
    k_gemm<<<9, 256, 0, stream>>>(wout_p + 2048, nullptr, 3 * HH, wwattT, HH, nullptr,
                                  nullptr, Wcomb + 2048, nullptr, nullptr, KC, NOP, 256, HH, 224, flagbar);
    k_bcomb<<<1, 256, 0, stream>>>(wout_p, b_out, b_att, b_watt, bcomb, flagbar);

    (void)hipFuncSetAttribute((const void*)k_persist,
                              hipFuncAttributeMaxDynamicSharedMemorySize, 131072);
    k_persist<<<NWG, 256, 131072, stream>>>(encbf, wordsbf, wattT, whh_bf, wih_p,
                                            b_ih, b_hh, Wcomb, bcomb, pp_pad, pose_pad,
                                            hF0, hF1, hhi0, hhi1, hlo0, hlo1,
                                            gcat, d_out, flagbar);
}

// Round 6
// 27987.961 us; speedup vs baseline: 1.2550x; 1.0046x over previous
//
#include <hip/hip_runtime.h>
#include <cstdint>
#include <cstddef>

typedef unsigned short ushort_t;
typedef __attribute__((ext_vector_type(8))) short short8;
typedef __attribute__((ext_vector_type(4))) float floatx4;

#define SS 128
#define BB 64
#define EE 1024
#define HH 1024
#define OO 135
#define WLW 64
#define PLP 32
#define TT 100
#define KP 160    // padded pose K (135 -> 160)
#define KC 2272   // combined K: 1024 (h) + 1024 (esum) + 224 (wsum)
#define NOP 144   // padded pose out dim
#define NWG 64    // persistent grid size (co-resident)

// LDS layout (dynamic, 131072 B total)
#define WHH_PITCH 1032
#define WIH_PITCH 168
#define LDS_WHH   0              // 48 rows * 1032 * 2B = 99072
#define LDS_WIH   99072          // 48 rows * 168 * 2B  = 16128
#define LDS_GS    115200         // 1280 f32 = 5120
#define LDS_CX    120320         // 2304 f32 = 9216
#define LDS_SC    129536         // 192 f32
#define LDS_WTS   130304         // 192 f32  -> end 131072

// flagbar layout (u32 indices; separate 128B lines)
#define FB_DTYPE 0
#define FB_BAR   32
#define FB_GEN   64

static __device__ __forceinline__ float bf2f(ushort_t u) {
    union { unsigned int i; float f; } v; v.i = ((unsigned int)u) << 16; return v.f;
}
static __device__ __forceinline__ ushort_t f2bf(float f) {
    union { float f; unsigned int i; } v; v.f = f;
    unsigned int x = v.i;
    x += 0x7fffu + ((x >> 16) & 1u);   // RNE
    return (ushort_t)(x >> 16);
}
static __device__ __forceinline__ float ldf(const void* p, long i, unsigned isbf) {
    if (isbf) return bf2f(((const ushort_t*)p)[i]);
    return ((const float*)p)[i];
}
static __device__ __forceinline__ short8 ldfrag(const ushort_t* p) {
    return *reinterpret_cast<const short8*>(p);
}
static __device__ __forceinline__ short8 ldfrag_l(const short* p) {
    return *reinterpret_cast<const short8*>(p);
}
static __device__ __forceinline__ floatx4 mfma(short8 a, short8 b, floatx4 c) {
    return __builtin_amdgcn_mfma_f32_16x16x32_bf16(a, b, c, 0, 0, 0);
}
static __device__ __forceinline__ float sigmoidf(float x) {
    x = fminf(fmaxf(x, -30.f), 30.f);
    return 1.f / (1.f + __expf(-x));
}
static __device__ __forceinline__ float tanh_f(float x) {
    x = fminf(fmaxf(x, -15.f), 15.f);
    float e = __expf(2.f * x);
    return (e - 1.f) / (e + 1.f);
}

// Device-wide generation barrier.
// SIGNAL path at SYSTEM scope (bypasses per-XCD L2 -> promptly visible across
// XCDs; R5's agent-scope plain load/store polled a stale local-L2 copy until
// eviction => ~84us/barrier + huge replay variance).
// DATA path: one agent release fence (wb L2) before arrival, one agent acquire
// fence (inv L2) after the flip is observed.
static __device__ __forceinline__ void gbar(unsigned* bar, unsigned* gen) {
    __syncthreads();
    if (threadIdx.x == 0) {
        unsigned g = __hip_atomic_load(gen, __ATOMIC_RELAXED, __HIP_MEMORY_SCOPE_SYSTEM);
        __builtin_amdgcn_fence(__ATOMIC_RELEASE, "agent");   // publish prior writes (wb L2)
        unsigned a = __hip_atomic_fetch_add(bar, 1u, __ATOMIC_RELAXED, __HIP_MEMORY_SCOPE_SYSTEM);
        if (a == NWG - 1u) {
            __hip_atomic_store(bar, 0u, __ATOMIC_RELAXED, __HIP_MEMORY_SCOPE_SYSTEM);
            // RELEASE orders the bar reset before the flip at the coherence point
            __hip_atomic_store(gen, g + 1u, __ATOMIC_RELEASE, __HIP_MEMORY_SCOPE_SYSTEM);
        } else {
            unsigned c;
            do {
                __builtin_amdgcn_s_sleep(8);
                c = __hip_atomic_load(gen, __ATOMIC_RELAXED, __HIP_MEMORY_SCOPE_SYSTEM);
            } while (c == g);
        }
        __builtin_amdgcn_fence(__ATOMIC_ACQUIRE, "agent");   // inv L2 once, after the wait
    }
    __syncthreads();
}

// ---------------- dtype detect + barrier init ----------------
__global__ void k_detect(const unsigned* __restrict__ enc, unsigned* __restrict__ flag)
{
    __shared__ int cnt;
    if (threadIdx.x == 0) cnt = 0;
    __syncthreads();
    unsigned w = enc[threadIdx.x];
    unsigned ef = (w >> 7) & 0xFFu;
    if (ef >= 0x70u && ef <= 0x81u) atomicAdd(&cnt, 1);
    __syncthreads();
    if (threadIdx.x == 0) {
        flag[FB_DTYPE] = (cnt >= 200) ? 1u : 0u;
        flag[FB_BAR] = 0u;
        flag[FB_GEN] = 0u;
    }
}

// ---------------- prep: pack/pad/transpose/convert inputs ----------------
__global__ void k_prep(const void* __restrict__ eh, const void* __restrict__ Watt,
                       const void* __restrict__ Wwatt, const void* __restrict__ Wih,
                       const void* __restrict__ Wout, const void* __restrict__ pp,
                       const void* __restrict__ Whh, const void* __restrict__ Wed,
                       const void* __restrict__ enc, const void* __restrict__ words,
                       ushort_t* __restrict__ ehcat, ushort_t* __restrict__ wattT,
                       ushort_t* __restrict__ wwattT, ushort_t* __restrict__ wih_p,
                       ushort_t* __restrict__ wout_p, ushort_t* __restrict__ pp_pad,
                       ushort_t* __restrict__ pose_pad, ushort_t* __restrict__ Wcomb,
                       ushort_t* __restrict__ whh_bf, ushort_t* __restrict__ wed_bf,
                       ushort_t* __restrict__ encbf, ushort_t* __restrict__ wordsbf,
                       const unsigned* __restrict__ flag)
{
    unsigned isbf = flag[FB_DTYPE];
    long idx = (long)blockIdx.x * 256 + threadIdx.x;
    const long n1 = BB * EE;
    const long n2 = (long)HH * EE;
    const long n3 = (long)256 * HH;
    const long n4 = (long)3 * HH * KP;
    const long n5 = (long)NOP * 3 * HH;
    const long n6 = (long)PLP * BB * KP;
    const long n7 = (long)BB * KP;
    const long n8 = (long)NOP * 1024;
    const long n9 = (long)3 * HH * HH;
    const long n10 = (long)HH * EE;
    const long n11 = (long)SS * BB * EE;
    const long n12 = (long)WLW * BB * 200;
    if (idx < n1) {
        int b = (int)(idx >> 10), r = (int)(idx & 1023);
        int c = r >> 9, jj = r & 511;
        ehcat[idx] = f2bf(ldf(eh, (long)(c * BB + b) * 512 + jj, isbf));
        return;
    }
    idx -= n1;
    if (idx < n2) {
        long e = idx >> 10, j = idx & 1023;
        wattT[idx] = f2bf(ldf(Watt, j * 1024 + e, isbf)); return;
    }
    idx -= n2;
    if (idx < n3) {
        long e = idx >> 10, j = idx & 1023;
        wwattT[idx] = (e < 200) ? f2bf(ldf(Wwatt, j * 200 + e, isbf)) : (ushort_t)0; return;
    }
    idx -= n3;
    if (idx < n4) {
        long row = idx / KP, k = idx % KP;
        wih_p[idx] = (k < OO) ? f2bf(ldf(Wih, row * OO + k, isbf)) : (ushort_t)0; return;
    }
    idx -= n4;
    if (idx < n5) {
        long row = idx / (3 * HH), k = idx % (3 * HH);
        wout_p[idx] = (row < OO) ? f2bf(ldf(Wout, row * (3 * HH) + k, isbf)) : (ushort_t)0; return;
    }
    idx -= n5;
    if (idx < n6) {
        long t = idx / (BB * KP); long rem = idx % (BB * KP);
        long b = rem / KP, k = rem % KP;
        pp_pad[idx] = (k < OO) ? f2bf(ldf(pp, (t * BB + b) * OO + k, isbf)) : (ushort_t)0; return;
    }
    idx -= n6;
    if (idx < n7) { pose_pad[idx] = 0; return; }
    idx -= n7;
    if (idx < n8) {
        long o = idx >> 10, j = idx & 1023;
        Wcomb[o * KC + j] = (o < OO) ? f2bf(ldf(Wout, o * (3 * HH) + j, isbf)) : (ushort_t)0; return;
    }
    idx -= n8;
    if (idx < n9) { whh_bf[idx] = f2bf(ldf(Whh, idx, isbf)); return; }
    idx -= n9;
    if (idx < n10) { wed_bf[idx] = f2bf(ldf(Wed, idx, isbf)); return; }
    idx -= n10;
    if (idx < n11) { encbf[idx] = f2bf(ldf(enc, idx, isbf)); return; }
    idx -= n11;
    if (idx < n12) { wordsbf[idx] = f2bf(ldf(words, idx, isbf)); return; }
}

// ---------------- generic MFMA GEMM (one-time uses) ----------------
__global__ void __launch_bounds__(256) k_gemm(
    const ushort_t* __restrict__ A, const ushort_t* __restrict__ Alo, int lda,
    const ushort_t* __restrict__ Bw, int ldb,
    const void* __restrict__ biasRaw,
    float* __restrict__ outF, ushort_t* __restrict__ outB,
    ushort_t* __restrict__ outHi, ushort_t* __restrict__ outLo,
    int ldo, int M, int N, int K, int ncap, const unsigned* __restrict__ flag)
{
    unsigned isbf = flag[FB_DTYPE];
    int lane = threadIdx.x & 63;
    int wid = (blockIdx.x << 2) + (threadIdx.x >> 6);
    int ng = N >> 6;
    int mt = wid / ng, g = wid % ng;
    if (mt * 16 >= M) return;
    int col = lane & 15, quad = lane >> 4;
    const ushort_t* ap = A + (size_t)(mt * 16 + col) * lda + quad * 8;
    const ushort_t* alp = Alo ? (Alo + (size_t)(mt * 16 + col) * lda + quad * 8) : (const ushort_t*)0;
    const ushort_t* bp = Bw + (size_t)((g << 6) + col) * ldb + quad * 8;
    floatx4 ac0 = {0.f, 0.f, 0.f, 0.f}, ac1 = ac0, ac2 = ac0, ac3 = ac0;
    if (alp) {
        for (int k = 0; k < K; k += 32) {
            short8 a = ldfrag(ap + k), al = ldfrag(alp + k);
            short8 f0 = ldfrag(bp + k);
            short8 f1 = ldfrag(bp + (size_t)16 * ldb + k);
            short8 f2 = ldfrag(bp + (size_t)32 * ldb + k);
            short8 f3 = ldfrag(bp + (size_t)48 * ldb + k);
            ac0 = mfma(a, f0, ac0); ac0 = mfma(al, f0, ac0);
            ac1 = mfma(a, f1, ac1); ac1 = mfma(al, f1, ac1);
            ac2 = mfma(a, f2, ac2); ac2 = mfma(al, f2, ac2);
            ac3 = mfma(a, f3, ac3); ac3 = mfma(al, f3, ac3);
        }
    } else {
        for (int k = 0; k < K; k += 32) {
            short8 a = ldfrag(ap + k);
            ac0 = mfma(a, ldfrag(bp + k), ac0);
            ac1 = mfma(a, ldfrag(bp + (size_t)16 * ldb + k), ac1);
            ac2 = mfma(a, ldfrag(bp + (size_t)32 * ldb + k), ac2);
            ac3 = mfma(a, ldfrag(bp + (size_t)48 * ldb + k), ac3);
        }
    }
    int m0 = mt * 16 + quad * 4;
    #pragma unroll
    for (int tIdx = 0; tIdx < 4; ++tIdx) {
        floatx4 ac = (tIdx == 0) ? ac0 : (tIdx == 1) ? ac1 : (tIdx == 2) ? ac2 : ac3;
        int n = (g << 6) + tIdx * 16 + col;
        if (n >= ncap) continue;
        float bv = biasRaw ? ldf(biasRaw, n, isbf) : 0.f;
        #pragma unroll
        for (int r = 0; r < 4; ++r) {
            float v = ac[r] + bv;
            size_t o = (size_t)(m0 + r) * ldo + n;
            if (outF) outF[o] = v;
            if (outB) outB[o] = f2bf(v);
            if (outHi) {
                ushort_t hi = f2bf(v);
                outHi[o] = hi;
                outLo[o] = f2bf(v - bf2f(hi));
            }
        }
    }
}

// ---------------- bcomb = b_out + Wout2 @ b_att + Wout3 @ b_watt ----------------
__global__ void k_bcomb(const ushort_t* __restrict__ wout_p, const void* __restrict__ b_out,
                        const void* __restrict__ b_att, const void* __restrict__ b_watt,
                        float* __restrict__ bcomb, const unsigned* __restrict__ flag)
{
    unsigned isbf = flag[FB_DTYPE];
    int o = threadIdx.x;
    if (o >= NOP) return;
    float s = (o < OO) ? ldf(b_out, o, isbf) : 0.f;
    const ushort_t* r2 = wout_p + (size_t)o * (3 * HH) + 1024;
    const ushort_t* r3 = wout_p + (size_t)o * (3 * HH) + 2048;
    for (int j = 0; j < HH; ++j) {
        s += bf2f(r2[j]) * ldf(b_att, j, isbf);
        s += bf2f(r3[j]) * ldf(b_watt, j, isbf);
    }
    bcomb[o] = s;
}

// ---------------- persistent decoder: 132 steps, phases GRU | gcat | attn+pose ----------------
__global__ void __launch_bounds__(256, 1) k_persist(
    const ushort_t* __restrict__ encbf, const ushort_t* __restrict__ wordsbf,
    const ushort_t* __restrict__ wattT,
    const ushort_t* __restrict__ whh_bf, const ushort_t* __restrict__ wih_p,
    const void* __restrict__ b_ih, const void* __restrict__ b_hh,
    const ushort_t* __restrict__ Wcomb, const float* __restrict__ bcomb,
    const ushort_t* __restrict__ pp_pad, ushort_t* __restrict__ pose_pad,
    float* hFa, float* hFb, ushort_t* hhia, ushort_t* hhib,
    ushort_t* hloa, ushort_t* hlob,
    float* __restrict__ gcat, void* __restrict__ out, unsigned* flagbar)
{
    extern __shared__ char smem[];
    short* whh_lds = (short*)(smem + LDS_WHH);
    short* wih_lds = (short*)(smem + LDS_WIH);
    float* gs  = (float*)(smem + LDS_GS);
    float* cx  = (float*)(smem + LDS_CX);
    float* sc  = (float*)(smem + LDS_SC);
    float* wts = (float*)(smem + LDS_WTS);

    const int tid = threadIdx.x;
    const int lane = tid & 63, wv = tid >> 6;
    const int wg = blockIdx.x;
    const int col = lane & 15, quad = lane >> 4;
    unsigned isbf = flagbar[FB_DTYPE];
    unsigned* bar = flagbar + FB_BAR;
    unsigned* gen = flagbar + FB_GEN;

    float* hFs = hFa; float* hFd = hFb;
    ushort_t* hhis = hhia; ushort_t* hhid = hhib;
    ushort_t* hlos = hloa; ushort_t* hlod = hlob;

    // ---- stage this wg's GRU weight slice into LDS (once) ----
    for (int s = tid; s < 48 * 128; s += 256) {
        int r = s >> 7;
        int ko = (s & 127) << 3;
        int g = r >> 4, rr = r & 15;
        *(short8*)(whh_lds + r * WHH_PITCH + ko) =
            ldfrag(whh_bf + (size_t)g * HH * HH + (size_t)(wg * 16 + rr) * HH + ko);
    }
    for (int s = tid; s < 48 * 20; s += 256) {
        int r = s / 20;
        int ko = (s % 20) << 3;
        int g = r >> 4, rr = r & 15;
        *(short8*)(wih_lds + r * WIH_PITCH + ko) =
            ldfrag(wih_p + (size_t)g * HH * KP + (size_t)(wg * 16 + rr) * KP + ko);
    }
    __syncthreads();

    const int j = wg * 16 + col;
    const float bir = ldf(b_ih, j, isbf)          + ldf(b_hh, j, isbf);
    const float biz = ldf(b_ih, HH + j, isbf)     + ldf(b_hh, HH + j, isbf);
    const float bin = ldf(b_ih, 2 * HH + j, isbf);
    const float bhn = ldf(b_hh, 2 * HH + j, isbf);

    for (int t = 0; t < PLP + TT; ++t) {
        const bool dec = (t >= PLP);
        const ushort_t* poseA = (t < PLP)  ? (pp_pad + (size_t)t * BB * KP)
                              : (t == PLP) ? (pp_pad + (size_t)(PLP - 1) * BB * KP)
                                           : pose_pad;
        // ======== phase 1: GRU (wg = j-tile, weights from LDS) ========
        {
            const ushort_t* ah = hhis + (size_t)(wv * 16 + col) * HH + quad * 8;
            const ushort_t* al = hlos + (size_t)(wv * 16 + col) * HH + quad * 8;
            const short* w0 = whh_lds + (size_t)(0  + col) * WHH_PITCH + quad * 8;
            const short* w1 = whh_lds + (size_t)(16 + col) * WHH_PITCH + quad * 8;
            const short* w2 = whh_lds + (size_t)(32 + col) * WHH_PITCH + quad * 8;
            floatx4 aR = {0.f, 0.f, 0.f, 0.f}, aZ = aR, aNi = aR, aNh = aR;
            for (int k = 0; k < HH; k += 32) {
                short8 f0 = ldfrag_l(w0 + k), f1 = ldfrag_l(w1 + k), f2 = ldfrag_l(w2 + k);
                short8 xh = ldfrag(ah + k), xl = ldfrag(al + k);
                aR = mfma(xh, f0, aR);   aR = mfma(xl, f0, aR);
                aZ = mfma(xh, f1, aZ);   aZ = mfma(xl, f1, aZ);
                aNh = mfma(xh, f2, aNh); aNh = mfma(xl, f2, aNh);
            }
            const ushort_t* ap = poseA + (size_t)(wv * 16 + col) * KP + quad * 8;
            const short* c0 = wih_lds + (size_t)(0  + col) * WIH_PITCH + quad * 8;
            const short* c1 = wih_lds + (size_t)(16 + col) * WIH_PITCH + quad * 8;
            const short* c2 = wih_lds + (size_t)(32 + col) * WIH_PITCH + quad * 8;
            for (int k = 0; k < KP; k += 32) {
                short8 xp = ldfrag(ap + k);
                aR = mfma(xp, ldfrag_l(c0 + k), aR);
                aZ = mfma(xp, ldfrag_l(c1 + k), aZ);
                aNi = mfma(xp, ldfrag_l(c2 + k), aNi);
            }
            #pragma unroll
            for (int r = 0; r < 4; ++r) {
                int b = wv * 16 + quad * 4 + r;
                float hold = hFs[(size_t)b * HH + j];
                float rg = sigmoidf(aR[r] + bir);
                float zg = sigmoidf(aZ[r] + biz);
                float ng = tanh_f(aNi[r] + bin + rg * (aNh[r] + bhn));
                float hn = (1.f - zg) * ng + zg * hold;
                hFd[(size_t)b * HH + j] = hn;
                ushort_t hi = f2bf(hn);
                hhid[(size_t)b * HH + j] = hi;
                hlod[(size_t)b * HH + j] = f2bf(hn - bf2f(hi));
            }
        }
        { float* tf = hFs; hFs = hFd; hFd = tf; }
        { ushort_t* tp = hhis; hhis = hhid; hhid = tp;
          tp = hlos; hlos = hlod; hlod = tp; }
        gbar(bar, gen);
        if (!dec) continue;

        // ======== phase 2: gcat = h @ [wattT|wwattT]^T (80 waves) ========
        {
            int wid = wg * 4 + wv;
            if (wid < 80) {
                int mt = wid / 20, g = wid % 20;
                const ushort_t* ap = hhis + (size_t)(mt * 16 + col) * HH + quad * 8;
                const ushort_t* alp = hlos + (size_t)(mt * 16 + col) * HH + quad * 8;
                const ushort_t* bp = wattT + (size_t)((g << 6) + col) * HH + quad * 8;
                floatx4 a0 = {0.f, 0.f, 0.f, 0.f}, a1 = a0, a2 = a0, a3 = a0;
                for (int k = 0; k < HH; k += 32) {
                    short8 xh = ldfrag(ap + k), xl = ldfrag(alp + k);
                    short8 f0 = ldfrag(bp + k);
                    short8 f1 = ldfrag(bp + (size_t)16 * HH + k);
                    short8 f2 = ldfrag(bp + (size_t)32 * HH + k);
                    short8 f3 = ldfrag(bp + (size_t)48 * HH + k);
                    a0 = mfma(xh, f0, a0); a0 = mfma(xl, f0, a0);
                    a1 = mfma(xh, f1, a1); a1 = mfma(xl, f1, a1);
                    a2 = mfma(xh, f2, a2); a2 = mfma(xl, f2, a2);
                    a3 = mfma(xh, f3, a3); a3 = mfma(xl, f3, a3);
                }
                int m0 = mt * 16 + quad * 4;
                #pragma unroll
                for (int ti2 = 0; ti2 < 4; ++ti2) {
                    floatx4 ac = (ti2 == 0) ? a0 : (ti2 == 1) ? a1 : (ti2 == 2) ? a2 : a3;
                    int n = (g << 6) + ti2 * 16 + col;
                    #pragma unroll
                    for (int r = 0; r < 4; ++r)
                        gcat[(size_t)(m0 + r) * 1280 + n] = ac[r];
                }
            }
        }
        gbar(bar, gen);

        // ======== phase 3: scores+softmax+ctx+pose (wg = batch) ========
        {
            const int b = wg;
            #pragma unroll
            for (int i = 0; i < 5; ++i) gs[tid + 256 * i] = gcat[(size_t)b * 1280 + tid + 256 * i];
            #pragma unroll
            for (int i = 0; i < 4; ++i) cx[tid + 256 * i] = hFs[(size_t)b * HH + tid + 256 * i];
            __syncthreads();
            for (int idx = wv; idx < 192; idx += 4) {
                float s = 0.f;
                if (idx < 128) {
                    const ushort_t* rp = encbf + ((size_t)(idx * BB + b) << 10);
                    #pragma unroll
                    for (int jj = 0; jj < 16; ++jj) {
                        int k = lane + (jj << 6);
                        s += bf2f(rp[k]) * gs[k];
                    }
                } else {
                    const ushort_t* rp = wordsbf + (size_t)((idx - 128) * BB + b) * 200;
                    #pragma unroll
                    for (int jj = 0; jj < 4; ++jj) {
                        int k = lane + (jj << 6);
                        if (k < 200) s += bf2f(rp[k]) * gs[1024 + k];
                    }
                }
                #pragma unroll
                for (int m = 1; m < 64; m <<= 1) s += __shfl_xor(s, m);
                if (lane == 0) sc[idx] = s;
            }
            __syncthreads();
            if (wv == 0) {
                float a = sc[lane], c = sc[lane + 64];
                float mx = fmaxf(a, c);
                #pragma unroll
                for (int m = 1; m < 64; m <<= 1) mx = fmaxf(mx, __shfl_xor(mx, m));
                float e0 = __expf(a - mx), e1 = __expf(c - mx);
                float sm = e0 + e1;
                #pragma unroll
                for (int m = 1; m < 64; m <<= 1) sm += __shfl_xor(sm, m);
                float inv = 1.f / sm;
                wts[lane] = e0 * inv; wts[lane + 64] = e1 * inv;
            } else if (wv == 1) {
                float a = sc[128 + lane];
                float mx = a;
                #pragma unroll
                for (int m = 1; m < 64; m <<= 1) mx = fmaxf(mx, __shfl_xor(mx, m));
                float e0 = __expf(a - mx);
                float sm = e0;
                #pragma unroll
                for (int m = 1; m < 64; m <<= 1) sm += __shfl_xor(sm, m);
                wts[128 + lane] = e0 / sm;
            }
            __syncthreads();
            float a0 = 0.f, a1 = 0.f, a2 = 0.f, a3 = 0.f;
            for (int s = 0; s < SS; ++s) {
                float w = wts[s];
                const ushort_t* rp = encbf + ((size_t)(s * BB + b) << 10) + tid;
                a0 += w * bf2f(rp[0]);   a1 += w * bf2f(rp[256]);
                a2 += w * bf2f(rp[512]); a3 += w * bf2f(rp[768]);
            }
            cx[1024 + tid] = a0; cx[1280 + tid] = a1;
            cx[1536 + tid] = a2; cx[1792 + tid] = a3;
            {
                float s224 = 0.f;
                if (tid < 200) {
                    for (int s = 0; s < WLW; ++s)
                        s224 += wts[128 + s] * bf2f(wordsbf[(size_t)(s * BB + b) * 200 + tid]);
                }
                cx[2048 + tid] = s224;
            }
            __syncthreads();
            int td = t - PLP;
            for (int oo = 0; oo < 36; ++oo) {
                int o = wv * 36 + oo;
                const ushort_t* wr = Wcomb + (size_t)o * KC;
                float s = 0.f;
                for (int i = 0; i < 36; ++i) {
                    int k = lane + (i << 6);
                    float wf = (k < KC) ? bf2f(wr[k]) : 0.f;
                    s += cx[k] * wf;
                }
                #pragma unroll
                for (int m = 1; m < 64; m <<= 1) s += __shfl_xor(s, m);
                if (lane == 0) {
                    float v = s + bcomb[o];
                    if (o < OO) {
                        size_t oi = ((size_t)td * BB + b) * OO + o;
                        if (isbf) ((ushort_t*)out)[oi] = f2bf(v);
                        else      ((float*)out)[oi] = v;
                    }
                    pose_pad[(size_t)b * KP + o] = (o < OO) ? f2bf(v) : (ushort_t)0;
                }
            }
        }
        gbar(bar, gen);
    }
}

extern "C" void kernel_launch(void* const* d_in, const int* in_sizes, int n_in,
                              void* d_out, int out_size, void* d_ws, size_t ws_size,
                              hipStream_t stream)
{
    (void)in_sizes; (void)n_in; (void)out_size; (void)ws_size;
    const void* enc_states = d_in[0];
    const void* enc_hidden = d_in[1];
    const void* prev_poses = d_in[2];
    const void* words      = d_in[3];
    const void* W_ed  = d_in[5];
    const void* b_ed  = d_in[6];
    const void* W_att = d_in[7];
    const void* b_att = d_in[8];
    const void* W_watt = d_in[9];
    const void* b_watt = d_in[10];
    const void* W_ih  = d_in[11];
    const void* W_hh  = d_in[12];
    const void* b_ih  = d_in[13];
    const void* b_hh  = d_in[14];
    const void* W_out = d_in[15];
    const void* b_out = d_in[16];

    char* base = (char*)d_ws;
    size_t off = 0;
    auto alloc = [&](size_t bytes) -> char* {
        char* p = base + off;
        off = (off + bytes + 255) & ~(size_t)255;
        return p;
    };
    unsigned* flagbar  = (unsigned*)alloc(512);
    ushort_t* ehcat    = (ushort_t*)alloc((size_t)BB * EE * 2);
    ushort_t* wattT    = (ushort_t*)alloc((size_t)HH * EE * 2);
    ushort_t* wwattT   = (ushort_t*)alloc((size_t)256 * HH * 2);  // contiguous after wattT
    ushort_t* wih_p    = (ushort_t*)alloc((size_t)3 * HH * KP * 2);
    ushort_t* wout_p   = (ushort_t*)alloc((size_t)NOP * 3 * HH * 2);
    ushort_t* pp_pad   = (ushort_t*)alloc((size_t)PLP * BB * KP * 2);
    ushort_t* pose_pad = (ushort_t*)alloc((size_t)BB * KP * 2);
    ushort_t* Wcomb    = (ushort_t*)alloc((size_t)NOP * KC * 2);
    float*    bcomb    = (float*)alloc((size_t)NOP * 4);
    ushort_t* whh_bf   = (ushort_t*)alloc((size_t)3 * HH * HH * 2);
    ushort_t* wed_bf   = (ushort_t*)alloc((size_t)HH * EE * 2);
    float*    hF0      = (float*)alloc((size_t)BB * HH * 4);
    float*    hF1      = (float*)alloc((size_t)BB * HH * 4);
    ushort_t* hhi0     = (ushort_t*)alloc((size_t)BB * HH * 2);
    ushort_t* hhi1     = (ushort_t*)alloc((size_t)BB * HH * 2);
    ushort_t* hlo0     = (ushort_t*)alloc((size_t)BB * HH * 2);
    ushort_t* hlo1     = (ushort_t*)alloc((size_t)BB * HH * 2);
    float*    gcat     = (float*)alloc((size_t)BB * 1280 * 4);
    ushort_t* encbf    = (ushort_t*)alloc((size_t)SS * BB * EE * 2);
    ushort_t* wordsbf  = (ushort_t*)alloc((size_t)WLW * BB * 200 * 2);

    k_detect<<<1, 256, 0, stream>>>((const unsigned*)enc_states, flagbar);

    k_prep<<<63272, 256, 0, stream>>>(enc_hidden, W_att, W_watt, W_ih, W_out, prev_poses,
                                      W_hh, W_ed, enc_states, words,
                                      ehcat, wattT, wwattT, wih_p, wout_p, pp_pad, pose_pad,
                                      Wcomb, whh_bf, wed_bf, encbf, wordsbf, flagbar);

    k_gemm<<<16, 256, 0, stream>>>(ehcat, nullptr, EE, wed_bf, EE, b_ed,
                                   hF0, nullptr, hhi0, hlo0, HH, BB, HH, EE, HH, flagbar);
    k_gemm<<<36, 256, 0, stream>>>(wout_p + 1024, nullptr, 3 * HH, wattT, HH, nullptr,
                                   nullptr, Wcomb + 1024, nullptr, nullptr, KC, NOP, HH, HH, HH, flagbar);
    k_gemm<<<9, 256, 0, stream>>>(wout_p + 2048, nullptr, 3 * HH, wwattT, HH, nullptr,
                                  nullptr, Wcomb + 2048, nullptr, nullptr, KC, NOP, 256, HH, 224, flagbar);
    k_bcomb<<<1, 256, 0, stream>>>(wout_p, b_out, b_att, b_watt, bcomb, flagbar);

    (void)hipFuncSetAttribute((const void*)k_persist,
                              hipFuncAttributeMaxDynamicSharedMemorySize, 131072);
    k_persist<<<NWG, 256, 131072, stream>>>(encbf, wordsbf, wattT, whh_bf, wih_p,
                                            b_ih, b_hh, Wcomb, bcomb, pp_pad, pose_pad,
                                            hF0, hF1, hhi0, hhi1, hlo0, hlo1,
                                            gcat, d_out, flagbar);
}

// Round 7
// 18417.621 us; speedup vs baseline: 1.9071x; 1.5196x over previous
//
#include <hip/hip_runtime.h>
#include <cstdint>
#include <cstddef>

typedef unsigned short ushort_t;
typedef __attribute__((ext_vector_type(8))) short short8;
typedef __attribute__((ext_vector_type(4))) float floatx4;

#define SS 128
#define BB 64
#define EE 1024
#define HH 1024
#define OO 135
#define WLW 64
#define PLP 32
#define TT 100
#define KP 160    // padded pose K (135 -> 160)
#define NWG 64    // persistent grid size (co-resident, 1 wg/CU at this LDS)

// LDS layout (dynamic, 129024 B total)
#define WHH_PITCH 1032
#define WIH_PITCH 168
#define LDS_WHH   0              // 48 rows * 1032 * 2B = 99072
#define LDS_WIH   99072          // 48 rows * 168 * 2B  = 16128
#define LDS_CX    115200         // 3072 f32 = 12288  (h | ctx | wctx)
#define LDS_SC    127488         // 192 f32
#define LDS_WTS   128256         // 192 f32 -> end 129024

// flagbar layout (u32 indices; separate 128B lines)
#define FB_DTYPE 0
#define FB_BAR   32
#define FB_GEN   64

static __device__ __forceinline__ float bf2f(ushort_t u) {
    union { unsigned int i; float f; } v; v.i = ((unsigned int)u) << 16; return v.f;
}
static __device__ __forceinline__ ushort_t f2bf(float f) {
    union { float f; unsigned int i; } v; v.f = f;
    unsigned int x = v.i;
    x += 0x7fffu + ((x >> 16) & 1u);   // RNE
    return (ushort_t)(x >> 16);
}
static __device__ __forceinline__ float ldf(const void* p, long i, unsigned isbf) {
    if (isbf) return bf2f(((const ushort_t*)p)[i]);
    return ((const float*)p)[i];
}
static __device__ __forceinline__ short8 ldfrag(const ushort_t* p) {
    return *reinterpret_cast<const short8*>(p);
}
static __device__ __forceinline__ short8 ldfrag_l(const short* p) {
    return *reinterpret_cast<const short8*>(p);
}
// fragment loader from a maybe-raw (fp32) source; kcap%8==0 so fragments never straddle
static __device__ __forceinline__ short8 frag_ld(const void* p, unsigned isbf,
                                                 long rowoff, int kbase, int kcap) {
    if (kbase >= kcap) {
        short8 z = {0, 0, 0, 0, 0, 0, 0, 0};
        return z;
    }
    if (isbf) return ldfrag((const ushort_t*)p + rowoff + kbase);
    const float* f = (const float*)p + rowoff + kbase;
    short8 a;
    #pragma unroll
    for (int i = 0; i < 8; ++i) a[i] = (short)f2bf(f[i]);
    return a;
}
static __device__ __forceinline__ floatx4 mfma(short8 a, short8 b, floatx4 c) {
    return __builtin_amdgcn_mfma_f32_16x16x32_bf16(a, b, c, 0, 0, 0);
}
static __device__ __forceinline__ float sigmoidf(float x) {
    x = fminf(fmaxf(x, -30.f), 30.f);
    return 1.f / (1.f + __expf(-x));
}
static __device__ __forceinline__ float tanh_f(float x) {
    x = fminf(fmaxf(x, -15.f), 15.f);
    float e = __expf(2.f * x);
    return (e - 1.f) / (e + 1.f);
}

// Device-wide generation barrier.
// KEY CHANGE (R7): every signal access is an atomic RMW (fetch_add), which must
// execute at the coherence point -- a relaxed LOAD can legally be served from the
// local (stale) XCD L2 until eviction, which measured as the flat ~84us/barrier
// in R4/R5/R6. Data path: one agent release fence (wb) before arrival, one agent
// acquire fence (inv) after the flip is observed.
static __device__ __forceinline__ void gbar(unsigned* bar, unsigned* gen) {
    __syncthreads();
    if (threadIdx.x == 0) {
        unsigned g = __hip_atomic_fetch_add(gen, 0u, __ATOMIC_RELAXED, __HIP_MEMORY_SCOPE_SYSTEM);
        __builtin_amdgcn_fence(__ATOMIC_RELEASE, "agent");   // publish prior writes
        unsigned a = __hip_atomic_fetch_add(bar, 1u, __ATOMIC_RELAXED, __HIP_MEMORY_SCOPE_SYSTEM);
        if (a == NWG - 1u) {
            __hip_atomic_store(bar, 0u, __ATOMIC_RELAXED, __HIP_MEMORY_SCOPE_SYSTEM);
            __hip_atomic_fetch_add(gen, 1u, __ATOMIC_RELEASE, __HIP_MEMORY_SCOPE_SYSTEM);
        } else {
            unsigned c;
            do {
                __builtin_amdgcn_s_sleep(2);
                c = __hip_atomic_fetch_add(gen, 0u, __ATOMIC_RELAXED, __HIP_MEMORY_SCOPE_SYSTEM);
            } while (c == g);
        }
        __builtin_amdgcn_fence(__ATOMIC_ACQUIRE, "agent");   // inv once, after the wait
    }
    __syncthreads();
}

// ---------------- dtype detect + barrier init ----------------
__global__ void k_detect(const unsigned* __restrict__ enc, unsigned* __restrict__ flag)
{
    __shared__ int cnt;
    if (threadIdx.x == 0) cnt = 0;
    __syncthreads();
    unsigned w = enc[threadIdx.x];
    unsigned ef = (w >> 7) & 0xFFu;
    if (ef >= 0x70u && ef <= 0x81u) atomicAdd(&cnt, 1);
    __syncthreads();
    if (threadIdx.x == 0) {
        flag[FB_DTYPE] = (cnt >= 200) ? 1u : 0u;
        flag[FB_BAR] = 0u;
        flag[FB_GEN] = 0u;
    }
}

// ---------------- prep: pack/pad/convert ----------------
__global__ void k_prep(const void* __restrict__ eh, const void* __restrict__ Wih,
                       const void* __restrict__ Wout, const void* __restrict__ pp,
                       const void* __restrict__ Whh,
                       ushort_t* __restrict__ ehcat, ushort_t* __restrict__ wih_p,
                       ushort_t* __restrict__ wout_p, ushort_t* __restrict__ pp_pad,
                       ushort_t* __restrict__ pose_pad, ushort_t* __restrict__ whh_bf,
                       const unsigned* __restrict__ flag)
{
    unsigned isbf = flag[FB_DTYPE];
    long idx = (long)blockIdx.x * 256 + threadIdx.x;
    const long n1 = BB * EE;             // 65536   ehcat
    const long n2 = (long)3 * HH * KP;   // 491520  wih_p
    const long n3 = (long)OO * 3 * HH;   // wout_p (135 rows only; we keep 144-row buffer but fill 135; pose loop guards o<144 reads -> fill 144)
    const long n3f = (long)144 * 3 * HH; // 442368  wout_p padded rows
    const long n4 = (long)PLP * BB * KP; // 327680  pp_pad
    const long n5 = (long)BB * KP;       // 10240   pose_pad
    const long n6 = (long)3 * HH * HH;   // 3145728 whh_bf
    (void)n3;
    if (idx < n1) {
        int b = (int)(idx >> 10), r = (int)(idx & 1023);
        int c = r >> 9, jj = r & 511;
        ehcat[idx] = f2bf(ldf(eh, (long)(c * BB + b) * 512 + jj, isbf));
        return;
    }
    idx -= n1;
    if (idx < n2) {
        long row = idx / KP, k = idx % KP;
        wih_p[idx] = (k < OO) ? f2bf(ldf(Wih, row * OO + k, isbf)) : (ushort_t)0; return;
    }
    idx -= n2;
    if (idx < n3f) {
        long row = idx / (3 * HH), k = idx % (3 * HH);
        wout_p[idx] = (row < OO) ? f2bf(ldf(Wout, row * (3 * HH) + k, isbf)) : (ushort_t)0; return;
    }
    idx -= n3f;
    if (idx < n4) {
        long t = idx / (BB * KP); long rem = idx % (BB * KP);
        long b = rem / KP, k = rem % KP;
        pp_pad[idx] = (k < OO) ? f2bf(ldf(pp, (t * BB + b) * OO + k, isbf)) : (ushort_t)0; return;
    }
    idx -= n4;
    if (idx < n5) { pose_pad[idx] = 0; return; }
    idx -= n5;
    if (idx < n6) { whh_bf[idx] = f2bf(ldf(Whh, idx, isbf)); return; }
}

// ---------------- generic MFMA GEMM with maybe-raw operands (one-time uses) ----------------
// out[M][N] = A[M][K] @ B[N][K]^T + bias ; a_bf16/b_bf16: 1 = operand already bf16, 0 = use dtype flag
__global__ void __launch_bounds__(256) k_gemm(
    const void* __restrict__ A, int a_bf16, int lda, int kcapA,
    const void* __restrict__ B, int b_bf16, int ldb, int kcapB,
    const void* __restrict__ biasRaw,
    float* __restrict__ outF, ushort_t* __restrict__ outB16,
    ushort_t* __restrict__ outHi, ushort_t* __restrict__ outLo,
    int ldo, int M, int N, int K, const unsigned* __restrict__ flag)
{
    unsigned isbf = flag[FB_DTYPE];
    unsigned a_isbf = a_bf16 ? 1u : isbf;
    unsigned b_isbf = b_bf16 ? 1u : isbf;
    int lane = threadIdx.x & 63;
    int wid = (blockIdx.x << 2) + (threadIdx.x >> 6);
    int ng = N >> 6;
    int mt = wid / ng, g = wid % ng;
    if (mt * 16 >= M) return;
    int col = lane & 15, quad = lane >> 4;
    long arow = (long)(mt * 16 + col) * lda;
    long brow0 = (long)((g << 6) + col) * ldb;
    long brow1 = brow0 + (long)16 * ldb;
    long brow2 = brow0 + (long)32 * ldb;
    long brow3 = brow0 + (long)48 * ldb;
    int kb = quad * 8;
    floatx4 ac0 = {0.f, 0.f, 0.f, 0.f}, ac1 = ac0, ac2 = ac0, ac3 = ac0;
    for (int k = 0; k < K; k += 32) {
        short8 av = frag_ld(A, a_isbf, arow, kb + k, kcapA);
        ac0 = mfma(av, frag_ld(B, b_isbf, brow0, kb + k, kcapB), ac0);
        ac1 = mfma(av, frag_ld(B, b_isbf, brow1, kb + k, kcapB), ac1);
        ac2 = mfma(av, frag_ld(B, b_isbf, brow2, kb + k, kcapB), ac2);
        ac3 = mfma(av, frag_ld(B, b_isbf, brow3, kb + k, kcapB), ac3);
    }
    int m0 = mt * 16 + quad * 4;
    #pragma unroll
    for (int tIdx = 0; tIdx < 4; ++tIdx) {
        floatx4 ac = (tIdx == 0) ? ac0 : (tIdx == 1) ? ac1 : (tIdx == 2) ? ac2 : ac3;
        int n = (g << 6) + tIdx * 16 + col;
        float bv = biasRaw ? ldf(biasRaw, n, isbf) : 0.f;
        #pragma unroll
        for (int r = 0; r < 4; ++r) {
            float v = ac[r] + bv;
            size_t o = (size_t)(m0 + r) * ldo + n;
            if (outF) outF[o] = v;
            if (outB16) outB16[o] = f2bf(v);
            if (outHi) {
                ushort_t hi = f2bf(v);
                outHi[o] = hi;
                outLo[o] = f2bf(v - bf2f(hi));
            }
        }
    }
}

// ---------------- persistent decoder: 132 steps, phases GRU | attn+pose ----------------
__global__ void __launch_bounds__(256, 1) k_persist(
    const ushort_t* __restrict__ encP,    // [S*B][1024] bf16, includes b_att
    const ushort_t* __restrict__ wordP,   // [WL*B][1024] bf16, includes b_watt
    const ushort_t* __restrict__ whh_bf, const ushort_t* __restrict__ wih_p,
    const void* __restrict__ b_ih, const void* __restrict__ b_hh,
    const ushort_t* __restrict__ wout_p,  // [144][3072] bf16
    const void* __restrict__ b_out,
    const ushort_t* __restrict__ pp_pad, ushort_t* __restrict__ pose_pad,
    float* hFa, float* hFb, ushort_t* hhia, ushort_t* hhib,
    ushort_t* hloa, ushort_t* hlob,
    void* __restrict__ out, unsigned* flagbar)
{
    extern __shared__ char smem[];
    short* whh_lds = (short*)(smem + LDS_WHH);
    short* wih_lds = (short*)(smem + LDS_WIH);
    float* cx  = (float*)(smem + LDS_CX);   // [0,1024): h ; [1024,2048): ctx ; [2048,3072): wctx
    float* sc  = (float*)(smem + LDS_SC);
    float* wts = (float*)(smem + LDS_WTS);

    const int tid = threadIdx.x;
    const int lane = tid & 63, wv = tid >> 6;
    const int wg = blockIdx.x;
    const int col = lane & 15, quad = lane >> 4;
    unsigned isbf = flagbar[FB_DTYPE];
    unsigned* bar = flagbar + FB_BAR;
    unsigned* gen = flagbar + FB_GEN;

    float* hFs = hFa; float* hFd = hFb;
    ushort_t* hhis = hhia; ushort_t* hhid = hhib;
    ushort_t* hlos = hloa; ushort_t* hlod = hlob;

    // ---- stage this wg's GRU weight slice into LDS (once) ----
    for (int s = tid; s < 48 * 128; s += 256) {
        int r = s >> 7;
        int ko = (s & 127) << 3;
        int g = r >> 4, rr = r & 15;
        *(short8*)(whh_lds + r * WHH_PITCH + ko) =
            ldfrag(whh_bf + (size_t)g * HH * HH + (size_t)(wg * 16 + rr) * HH + ko);
    }
    for (int s = tid; s < 48 * 20; s += 256) {
        int r = s / 20;
        int ko = (s % 20) << 3;
        int g = r >> 4, rr = r & 15;
        *(short8*)(wih_lds + r * WIH_PITCH + ko) =
            ldfrag(wih_p + (size_t)g * HH * KP + (size_t)(wg * 16 + rr) * KP + ko);
    }
    __syncthreads();

    const int j = wg * 16 + col;
    const float bir = ldf(b_ih, j, isbf)          + ldf(b_hh, j, isbf);
    const float biz = ldf(b_ih, HH + j, isbf)     + ldf(b_hh, HH + j, isbf);
    const float bin = ldf(b_ih, 2 * HH + j, isbf);
    const float bhn = ldf(b_hh, 2 * HH + j, isbf);

    for (int t = 0; t < PLP + TT; ++t) {
        const bool dec = (t >= PLP);
        const ushort_t* poseA = (t < PLP)  ? (pp_pad + (size_t)t * BB * KP)
                              : (t == PLP) ? (pp_pad + (size_t)(PLP - 1) * BB * KP)
                                           : pose_pad;
        // ======== phase A: GRU (wg = j-tile, weights from LDS) ========
        {
            const ushort_t* ah = hhis + (size_t)(wv * 16 + col) * HH + quad * 8;
            const ushort_t* al = hlos + (size_t)(wv * 16 + col) * HH + quad * 8;
            const short* w0 = whh_lds + (size_t)(0  + col) * WHH_PITCH + quad * 8;
            const short* w1 = whh_lds + (size_t)(16 + col) * WHH_PITCH + quad * 8;
            const short* w2 = whh_lds + (size_t)(32 + col) * WHH_PITCH + quad * 8;
            floatx4 aR = {0.f, 0.f, 0.f, 0.f}, aZ = aR, aNi = aR, aNh = aR;
            for (int k = 0; k < HH; k += 32) {
                short8 f0 = ldfrag_l(w0 + k), f1 = ldfrag_l(w1 + k), f2 = ldfrag_l(w2 + k);
                short8 xh = ldfrag(ah + k), xl = ldfrag(al + k);
                aR = mfma(xh, f0, aR);   aR = mfma(xl, f0, aR);
                aZ = mfma(xh, f1, aZ);   aZ = mfma(xl, f1, aZ);
                aNh = mfma(xh, f2, aNh); aNh = mfma(xl, f2, aNh);
            }
            const ushort_t* ap = poseA + (size_t)(wv * 16 + col) * KP + quad * 8;
            const short* c0 = wih_lds + (size_t)(0  + col) * WIH_PITCH + quad * 8;
            const short* c1 = wih_lds + (size_t)(16 + col) * WIH_PITCH + quad * 8;
            const short* c2 = wih_lds + (size_t)(32 + col) * WIH_PITCH + quad * 8;
            for (int k = 0; k < KP; k += 32) {
                short8 xp = ldfrag(ap + k);
                aR = mfma(xp, ldfrag_l(c0 + k), aR);
                aZ = mfma(xp, ldfrag_l(c1 + k), aZ);
                aNi = mfma(xp, ldfrag_l(c2 + k), aNi);
            }
            #pragma unroll
            for (int r = 0; r < 4; ++r) {
                int b = wv * 16 + quad * 4 + r;
                float hold = hFs[(size_t)b * HH + j];
                float rg = sigmoidf(aR[r] + bir);
                float zg = sigmoidf(aZ[r] + biz);
                float ng = tanh_f(aNi[r] + bin + rg * (aNh[r] + bhn));
                float hn = (1.f - zg) * ng + zg * hold;
                hFd[(size_t)b * HH + j] = hn;
                ushort_t hi = f2bf(hn);
                hhid[(size_t)b * HH + j] = hi;
                hlod[(size_t)b * HH + j] = f2bf(hn - bf2f(hi));
            }
        }
        { float* tf = hFs; hFs = hFd; hFd = tf; }
        { ushort_t* tp = hhis; hhis = hhid; hhid = tp;
          tp = hlos; hlos = hlod; hlod = tp; }
        gbar(bar, gen);
        if (!dec) continue;

        // ======== phase B: scores + softmax + ctx/wctx + pose (wg = batch) ========
        {
            const int b = wg;
            #pragma unroll
            for (int i = 0; i < 4; ++i) cx[tid + 256 * i] = hFs[(size_t)b * HH + tid + 256 * i];
            __syncthreads();
            for (int idx = wv; idx < 192; idx += 4) {
                const ushort_t* rp = (idx < 128)
                    ? (encP + ((size_t)(idx * BB + b) << 10))
                    : (wordP + ((size_t)((idx - 128) * BB + b) << 10));
                float s = 0.f;
                #pragma unroll
                for (int jj = 0; jj < 16; ++jj) {
                    int k = lane + (jj << 6);
                    s += bf2f(rp[k]) * cx[k];
                }
                #pragma unroll
                for (int m = 1; m < 64; m <<= 1) s += __shfl_xor(s, m);
                if (lane == 0) sc[idx] = s;
            }
            __syncthreads();
            if (wv == 0) {
                float a = sc[lane], c = sc[lane + 64];
                float mx = fmaxf(a, c);
                #pragma unroll
                for (int m = 1; m < 64; m <<= 1) mx = fmaxf(mx, __shfl_xor(mx, m));
                float e0 = __expf(a - mx), e1 = __expf(c - mx);
                float sm = e0 + e1;
                #pragma unroll
                for (int m = 1; m < 64; m <<= 1) sm += __shfl_xor(sm, m);
                float inv = 1.f / sm;
                wts[lane] = e0 * inv; wts[lane + 64] = e1 * inv;
            } else if (wv == 1) {
                float a = sc[128 + lane];
                float mx = a;
                #pragma unroll
                for (int m = 1; m < 64; m <<= 1) mx = fmaxf(mx, __shfl_xor(mx, m));
                float e0 = __expf(a - mx);
                float sm = e0;
                #pragma unroll
                for (int m = 1; m < 64; m <<= 1) sm += __shfl_xor(sm, m);
                wts[128 + lane] = e0 / sm;
            }
            __syncthreads();
            // ctx = sum_s wts[s] * encP[s][b][:]
            {
                float a0 = 0.f, a1 = 0.f, a2 = 0.f, a3 = 0.f;
                for (int s = 0; s < SS; ++s) {
                    float w = wts[s];
                    const ushort_t* rp = encP + ((size_t)(s * BB + b) << 10) + tid;
                    a0 += w * bf2f(rp[0]);   a1 += w * bf2f(rp[256]);
                    a2 += w * bf2f(rp[512]); a3 += w * bf2f(rp[768]);
                }
                cx[1024 + tid] = a0; cx[1280 + tid] = a1;
                cx[1536 + tid] = a2; cx[1792 + tid] = a3;
            }
            // wctx = sum_s wts[128+s] * wordP[s][b][:]
            {
                float a0 = 0.f, a1 = 0.f, a2 = 0.f, a3 = 0.f;
                for (int s = 0; s < WLW; ++s) {
                    float w = wts[128 + s];
                    const ushort_t* rp = wordP + ((size_t)(s * BB + b) << 10) + tid;
                    a0 += w * bf2f(rp[0]);   a1 += w * bf2f(rp[256]);
                    a2 += w * bf2f(rp[512]); a3 += w * bf2f(rp[768]);
                }
                cx[2048 + tid] = a0; cx[2304 + tid] = a1;
                cx[2560 + tid] = a2; cx[2816 + tid] = a3;
            }
            __syncthreads();
            // pose[o] = [h|ctx|wctx] . wout_p[o] + b_out[o]
            int td = t - PLP;
            for (int oo = 0; oo < 36; ++oo) {
                int o = wv * 36 + oo;
                const ushort_t* wr = wout_p + (size_t)o * (3 * HH);
                float s = 0.f;
                #pragma unroll 4
                for (int i = 0; i < 48; ++i) {
                    int k = lane + (i << 6);
                    s += bf2f(wr[k]) * cx[k];
                }
                #pragma unroll
                for (int m = 1; m < 64; m <<= 1) s += __shfl_xor(s, m);
                if (lane == 0) {
                    float v = s + ((o < OO) ? ldf(b_out, o, isbf) : 0.f);
                    if (o < OO) {
                        size_t oi = ((size_t)td * BB + b) * OO + o;
                        if (isbf) ((ushort_t*)out)[oi] = f2bf(v);
                        else      ((float*)out)[oi] = v;
                    }
                    pose_pad[(size_t)b * KP + o] = (o < OO) ? f2bf(v) : (ushort_t)0;
                }
            }
        }
        gbar(bar, gen);
    }
}

extern "C" void kernel_launch(void* const* d_in, const int* in_sizes, int n_in,
                              void* d_out, int out_size, void* d_ws, size_t ws_size,
                              hipStream_t stream)
{
    (void)in_sizes; (void)n_in; (void)out_size; (void)ws_size;
    const void* enc_states = d_in[0];
    const void* enc_hidden = d_in[1];
    const void* prev_poses = d_in[2];
    const void* words      = d_in[3];
    const void* W_ed  = d_in[5];
    const void* b_ed  = d_in[6];
    const void* W_att = d_in[7];
    const void* b_att = d_in[8];
    const void* W_watt = d_in[9];
    const void* b_watt = d_in[10];
    const void* W_ih  = d_in[11];
    const void* W_hh  = d_in[12];
    const void* b_ih  = d_in[13];
    const void* b_hh  = d_in[14];
    const void* W_out = d_in[15];
    const void* b_out = d_in[16];

    char* base = (char*)d_ws;
    size_t off = 0;
    auto alloc = [&](size_t bytes) -> char* {
        char* p = base + off;
        off = (off + bytes + 255) & ~(size_t)255;
        return p;
    };
    unsigned* flagbar  = (unsigned*)alloc(512);
    ushort_t* ehcat    = (ushort_t*)alloc((size_t)BB * EE * 2);          // 128 KB
    ushort_t* wih_p    = (ushort_t*)alloc((size_t)3 * HH * KP * 2);      // 960 KB
    ushort_t* wout_p   = (ushort_t*)alloc((size_t)144 * 3 * HH * 2);     // 864 KB
    ushort_t* pp_pad   = (ushort_t*)alloc((size_t)PLP * BB * KP * 2);    // 640 KB
    ushort_t* pose_pad = (ushort_t*)alloc((size_t)BB * KP * 2);          // 20 KB
    ushort_t* whh_bf   = (ushort_t*)alloc((size_t)3 * HH * HH * 2);      // 6 MB
    float*    hF0      = (float*)alloc((size_t)BB * HH * 4);
    float*    hF1      = (float*)alloc((size_t)BB * HH * 4);
    ushort_t* hhi0     = (ushort_t*)alloc((size_t)BB * HH * 2);
    ushort_t* hhi1     = (ushort_t*)alloc((size_t)BB * HH * 2);
    ushort_t* hlo0     = (ushort_t*)alloc((size_t)BB * HH * 2);
    ushort_t* hlo1     = (ushort_t*)alloc((size_t)BB * HH * 2);
    ushort_t* encP     = (ushort_t*)alloc((size_t)SS * BB * HH * 2);     // 16 MB
    ushort_t* wordP    = (ushort_t*)alloc((size_t)WLW * BB * HH * 2);    // 8 MB
    // total ~35.2 MB

    k_detect<<<1, 256, 0, stream>>>((const unsigned*)enc_states, flagbar);

    k_prep<<<17512, 256, 0, stream>>>(enc_hidden, W_ih, W_out, prev_poses, W_hh,
                                      ehcat, wih_p, wout_p, pp_pad, pose_pad, whh_bf,
                                      flagbar);

    // h0 = ehcat @ W_ed^T + b_ed    (M=64, N=1024, K=1024)
    k_gemm<<<16, 256, 0, stream>>>(ehcat, 1, EE, EE, W_ed, 0, EE, EE, b_ed,
                                   hF0, nullptr, hhi0, hlo0, HH, BB, HH, EE, flagbar);
    // encP = enc @ W_att^T + b_att  (M=8192, N=1024, K=1024)
    k_gemm<<<2048, 256, 0, stream>>>(enc_states, 0, EE, EE, W_att, 0, EE, EE, b_att,
                                     nullptr, encP, nullptr, nullptr, HH, SS * BB, HH, EE, flagbar);
    // wordP = words @ W_watt^T + b_watt  (M=4096, N=1024, K=224 cap 200)
    k_gemm<<<1024, 256, 0, stream>>>(words, 0, 200, 200, W_watt, 0, 200, 200, b_watt,
                                     nullptr, wordP, nullptr, nullptr, HH, WLW * BB, HH, 224, flagbar);

    (void)hipFuncSetAttribute((const void*)k_persist,
                              hipFuncAttributeMaxDynamicSharedMemorySize, 129024);
    k_persist<<<NWG, 256, 129024, stream>>>(encP, wordP, whh_bf, wih_p,
                                            b_ih, b_hh, wout_p, b_out, pp_pad, pose_pad,
                                            hF0, hF1, hhi0, hhi1, hlo0, hlo1,
                                            d_out, flagbar);
}

// Round 8
// 12212.843 us; speedup vs baseline: 2.8761x; 1.5081x over previous
//
#include <hip/hip_runtime.h>
#include <cstdint>
#include <cstddef>

typedef unsigned short ushort_t;
typedef __attribute__((ext_vector_type(8))) short short8;
typedef __attribute__((ext_vector_type(4))) float floatx4;

#define SS 128
#define BB 64
#define EE 1024
#define HH 1024
#define OO 135
#define WLW 64
#define PLP 32
#define TT 100
#define KP 160    // padded pose K (135 -> 160)
#define NWG 64    // persistent grid size (co-resident)

// LDS layout (dynamic, 129024 B total)
#define WHH_PITCH 1032
#define WIH_PITCH 168
#define LDS_WHH   0              // 48 rows * 1032 * 2B = 99072
#define LDS_WIH   99072          // 48 rows * 168 * 2B  = 16128
#define LDS_CX    115200         // 3072 f32 = 12288  (h | ctx | wctx)
#define LDS_SC    127488         // 192 f32
#define LDS_WTS   128256         // 192 f32 -> end 129024

// flagbar layout (u32 indices; separate 128B lines)
#define FB_DTYPE 0
#define FB_BAR   32

static __device__ __forceinline__ float bf2f(ushort_t u) {
    union { unsigned int i; float f; } v; v.i = ((unsigned int)u) << 16; return v.f;
}
static __device__ __forceinline__ ushort_t f2bf(float f) {
    union { float f; unsigned int i; } v; v.f = f;
    unsigned int x = v.i;
    x += 0x7fffu + ((x >> 16) & 1u);   // RNE
    return (ushort_t)(x >> 16);
}
static __device__ __forceinline__ float ldf(const void* p, long i, unsigned isbf) {
    if (isbf) return bf2f(((const ushort_t*)p)[i]);
    return ((const float*)p)[i];
}
static __device__ __forceinline__ short8 ldfrag(const ushort_t* p) {
    return *reinterpret_cast<const short8*>(p);
}
static __device__ __forceinline__ short8 ldfrag_l(const short* p) {
    return *reinterpret_cast<const short8*>(p);
}
// ---- system-scope (coherence-point) accessors: bypass non-coherent per-XCD L2 ----
static __device__ __forceinline__ unsigned long long sysld_u64(const void* p) {
    return __hip_atomic_load((const unsigned long long*)p, __ATOMIC_RELAXED, __HIP_MEMORY_SCOPE_SYSTEM);
}
static __device__ __forceinline__ void sysst_u16(ushort_t* p, ushort_t v) {
    __hip_atomic_store(p, v, __ATOMIC_RELAXED, __HIP_MEMORY_SCOPE_SYSTEM);
}
static __device__ __forceinline__ short8 sysld_frag16(const ushort_t* p) {
    union { unsigned long long u[2]; short8 s; } r;
    r.u[0] = sysld_u64(p);
    r.u[1] = sysld_u64(p + 4);
    return r.s;
}
// fragment loader from a maybe-raw (fp32) source; kcap%8==0
static __device__ __forceinline__ short8 frag_ld(const void* p, unsigned isbf,
                                                 long rowoff, int kbase, int kcap) {
    if (kbase >= kcap) {
        short8 z = {0, 0, 0, 0, 0, 0, 0, 0};
        return z;
    }
    if (isbf) return ldfrag((const ushort_t*)p + rowoff + kbase);
    const float* f = (const float*)p + rowoff + kbase;
    short8 a;
    #pragma unroll
    for (int i = 0; i < 8; ++i) a[i] = (short)f2bf(f[i]);
    return a;
}
static __device__ __forceinline__ floatx4 mfma(short8 a, short8 b, floatx4 c) {
    return __builtin_amdgcn_mfma_f32_16x16x32_bf16(a, b, c, 0, 0, 0);
}
static __device__ __forceinline__ float sigmoidf(float x) {
    x = fminf(fmaxf(x, -30.f), 30.f);
    return 1.f / (1.f + __expf(-x));
}
static __device__ __forceinline__ float tanh_f(float x) {
    x = fminf(fmaxf(x, -15.f), 15.f);
    float e = __expf(2.f * x);
    return (e - 1.f) / (e + 1.f);
}

// Device-wide ticket barrier. NO agent fences (no L2 wb/inv!) -- all cross-wg
// data moves via system-scope accessors; read-only arrays stay warm in L2.
// __syncthreads drains each wave's vmcnt (compiler emits full s_waitcnt before
// s_barrier), so the arrival RMW orders after this wg's system stores.
static __device__ __forceinline__ void gbar(unsigned* bar, unsigned target) {
    __syncthreads();
    if (threadIdx.x == 0) {
        __builtin_amdgcn_fence(__ATOMIC_RELEASE, "workgroup");   // compiler ordering only
        __hip_atomic_fetch_add(bar, 1u, __ATOMIC_RELAXED, __HIP_MEMORY_SCOPE_SYSTEM);
        unsigned c;
        do {
            __builtin_amdgcn_s_sleep(1);
            c = __hip_atomic_fetch_add(bar, 0u, __ATOMIC_RELAXED, __HIP_MEMORY_SCOPE_SYSTEM);
        } while (c < target);
        __builtin_amdgcn_fence(__ATOMIC_ACQUIRE, "workgroup");   // compiler ordering only
    }
    __syncthreads();
}

// ---------------- dtype detect + barrier init ----------------
__global__ void k_detect(const unsigned* __restrict__ enc, unsigned* __restrict__ flag)
{
    __shared__ int cnt;
    if (threadIdx.x == 0) cnt = 0;
    __syncthreads();
    unsigned w = enc[threadIdx.x];
    unsigned ef = (w >> 7) & 0xFFu;
    if (ef >= 0x70u && ef <= 0x81u) atomicAdd(&cnt, 1);
    __syncthreads();
    if (threadIdx.x == 0) {
        flag[FB_DTYPE] = (cnt >= 200) ? 1u : 0u;
        flag[FB_BAR] = 0u;
    }
}

// ---------------- prep: pack/pad/convert ----------------
__global__ void k_prep(const void* __restrict__ eh, const void* __restrict__ Wih,
                       const void* __restrict__ Wout, const void* __restrict__ pp,
                       const void* __restrict__ Whh,
                       ushort_t* __restrict__ ehcat, ushort_t* __restrict__ wih_p,
                       ushort_t* __restrict__ wout_p, ushort_t* __restrict__ pp_pad,
                       ushort_t* __restrict__ pose_pad, ushort_t* __restrict__ whh_bf,
                       const unsigned* __restrict__ flag)
{
    unsigned isbf = flag[FB_DTYPE];
    long idx = (long)blockIdx.x * 256 + threadIdx.x;
    const long n1 = BB * EE;
    const long n2 = (long)3 * HH * KP;
    const long n3f = (long)144 * 3 * HH;
    const long n4 = (long)PLP * BB * KP;
    const long n5 = (long)BB * KP;
    const long n6 = (long)3 * HH * HH;
    if (idx < n1) {
        int b = (int)(idx >> 10), r = (int)(idx & 1023);
        int c = r >> 9, jj = r & 511;
        ehcat[idx] = f2bf(ldf(eh, (long)(c * BB + b) * 512 + jj, isbf));
        return;
    }
    idx -= n1;
    if (idx < n2) {
        long row = idx / KP, k = idx % KP;
        wih_p[idx] = (k < OO) ? f2bf(ldf(Wih, row * OO + k, isbf)) : (ushort_t)0; return;
    }
    idx -= n2;
    if (idx < n3f) {
        long row = idx / (3 * HH), k = idx % (3 * HH);
        wout_p[idx] = (row < OO) ? f2bf(ldf(Wout, row * (3 * HH) + k, isbf)) : (ushort_t)0; return;
    }
    idx -= n3f;
    if (idx < n4) {
        long t = idx / (BB * KP); long rem = idx % (BB * KP);
        long b = rem / KP, k = rem % KP;
        pp_pad[idx] = (k < OO) ? f2bf(ldf(pp, (t * BB + b) * OO + k, isbf)) : (ushort_t)0; return;
    }
    idx -= n4;
    if (idx < n5) { pose_pad[idx] = 0; return; }
    idx -= n5;
    if (idx < n6) { whh_bf[idx] = f2bf(ldf(Whh, idx, isbf)); return; }
}

// ---------------- generic MFMA GEMM with maybe-raw operands (one-time uses) ----------------
__global__ void __launch_bounds__(256) k_gemm(
    const void* __restrict__ A, int a_bf16, int lda, int kcapA,
    const void* __restrict__ B, int b_bf16, int ldb, int kcapB,
    const void* __restrict__ biasRaw,
    float* __restrict__ outF, ushort_t* __restrict__ outB16,
    ushort_t* __restrict__ outHi, ushort_t* __restrict__ outLo,
    int ldo, int M, int N, int K, const unsigned* __restrict__ flag)
{
    unsigned isbf = flag[FB_DTYPE];
    unsigned a_isbf = a_bf16 ? 1u : isbf;
    unsigned b_isbf = b_bf16 ? 1u : isbf;
    int lane = threadIdx.x & 63;
    int wid = (blockIdx.x << 2) + (threadIdx.x >> 6);
    int ng = N >> 6;
    int mt = wid / ng, g = wid % ng;
    if (mt * 16 >= M) return;
    int col = lane & 15, quad = lane >> 4;
    long arow = (long)(mt * 16 + col) * lda;
    long brow0 = (long)((g << 6) + col) * ldb;
    long brow1 = brow0 + (long)16 * ldb;
    long brow2 = brow0 + (long)32 * ldb;
    long brow3 = brow0 + (long)48 * ldb;
    int kb = quad * 8;
    floatx4 ac0 = {0.f, 0.f, 0.f, 0.f}, ac1 = ac0, ac2 = ac0, ac3 = ac0;
    for (int k = 0; k < K; k += 32) {
        short8 av = frag_ld(A, a_isbf, arow, kb + k, kcapA);
        ac0 = mfma(av, frag_ld(B, b_isbf, brow0, kb + k, kcapB), ac0);
        ac1 = mfma(av, frag_ld(B, b_isbf, brow1, kb + k, kcapB), ac1);
        ac2 = mfma(av, frag_ld(B, b_isbf, brow2, kb + k, kcapB), ac2);
        ac3 = mfma(av, frag_ld(B, b_isbf, brow3, kb + k, kcapB), ac3);
    }
    int m0 = mt * 16 + quad * 4;
    #pragma unroll
    for (int tIdx = 0; tIdx < 4; ++tIdx) {
        floatx4 ac = (tIdx == 0) ? ac0 : (tIdx == 1) ? ac1 : (tIdx == 2) ? ac2 : ac3;
        int n = (g << 6) + tIdx * 16 + col;
        float bv = biasRaw ? ldf(biasRaw, n, isbf) : 0.f;
        #pragma unroll
        for (int r = 0; r < 4; ++r) {
            float v = ac[r] + bv;
            size_t o = (size_t)(m0 + r) * ldo + n;
            if (outF) outF[o] = v;
            if (outB16) outB16[o] = f2bf(v);
            if (outHi) {
                ushort_t hi = f2bf(v);
                outHi[o] = hi;
                outLo[o] = f2bf(v - bf2f(hi));
            }
        }
    }
}

// ---------------- persistent decoder: 132 steps, phases GRU | attn+pose ----------------
__global__ void __launch_bounds__(256, 1) k_persist(
    const ushort_t* __restrict__ encP,    // [S*B][1024] bf16, includes b_att (read-only, L2-warm)
    const ushort_t* __restrict__ wordP,   // [WL*B][1024] bf16, includes b_watt
    const ushort_t* __restrict__ whh_bf, const ushort_t* __restrict__ wih_p,
    const void* __restrict__ b_ih, const void* __restrict__ b_hh,
    const ushort_t* __restrict__ wout_p,  // [144][3072] bf16
    const void* __restrict__ b_out,
    const ushort_t* __restrict__ pp_pad, ushort_t* __restrict__ pose_pad,
    float* hFa, float* hFb, ushort_t* hhia, ushort_t* hhib,
    ushort_t* hloa, ushort_t* hlob,
    void* __restrict__ out, unsigned* flagbar)
{
    extern __shared__ char smem[];
    short* whh_lds = (short*)(smem + LDS_WHH);
    short* wih_lds = (short*)(smem + LDS_WIH);
    float* cx  = (float*)(smem + LDS_CX);   // [0,1024): h ; [1024,2048): ctx ; [2048,3072): wctx
    float* sc  = (float*)(smem + LDS_SC);
    float* wts = (float*)(smem + LDS_WTS);

    const int tid = threadIdx.x;
    const int lane = tid & 63, wv = tid >> 6;
    const int wg = blockIdx.x;
    const int col = lane & 15, quad = lane >> 4;
    unsigned isbf = flagbar[FB_DTYPE];
    unsigned* bar = flagbar + FB_BAR;
    unsigned btarget = 0;

    float* hFs = hFa; float* hFd = hFb;
    ushort_t* hhis = hhia; ushort_t* hhid = hhib;
    ushort_t* hlos = hloa; ushort_t* hlod = hlob;

    // ---- stage this wg's GRU weight slice into LDS (once) ----
    for (int s = tid; s < 48 * 128; s += 256) {
        int r = s >> 7;
        int ko = (s & 127) << 3;
        int g = r >> 4, rr = r & 15;
        *(short8*)(whh_lds + r * WHH_PITCH + ko) =
            ldfrag(whh_bf + (size_t)g * HH * HH + (size_t)(wg * 16 + rr) * HH + ko);
    }
    for (int s = tid; s < 48 * 20; s += 256) {
        int r = s / 20;
        int ko = (s % 20) << 3;
        int g = r >> 4, rr = r & 15;
        *(short8*)(wih_lds + r * WIH_PITCH + ko) =
            ldfrag(wih_p + (size_t)g * HH * KP + (size_t)(wg * 16 + rr) * KP + ko);
    }
    __syncthreads();

    const int j = wg * 16 + col;
    const float bir = ldf(b_ih, j, isbf)          + ldf(b_hh, j, isbf);
    const float biz = ldf(b_ih, HH + j, isbf)     + ldf(b_hh, HH + j, isbf);
    const float bin = ldf(b_ih, 2 * HH + j, isbf);
    const float bhn = ldf(b_hh, 2 * HH + j, isbf);

    for (int t = 0; t < PLP + TT; ++t) {
        const bool dec = (t >= PLP);
        const bool warm_src = (t <= PLP);
        const ushort_t* poseA = (t < PLP)  ? (pp_pad + (size_t)t * BB * KP)
                              : (t == PLP) ? (pp_pad + (size_t)(PLP - 1) * BB * KP)
                                           : pose_pad;
        // ======== phase A: GRU (wg = j-tile, weights from LDS) ========
        {
            const ushort_t* ah = hhis + (size_t)(wv * 16 + col) * HH + quad * 8;
            const ushort_t* al = hlos + (size_t)(wv * 16 + col) * HH + quad * 8;
            const short* w0 = whh_lds + (size_t)(0  + col) * WHH_PITCH + quad * 8;
            const short* w1 = whh_lds + (size_t)(16 + col) * WHH_PITCH + quad * 8;
            const short* w2 = whh_lds + (size_t)(32 + col) * WHH_PITCH + quad * 8;
            floatx4 aR = {0.f, 0.f, 0.f, 0.f}, aZ = aR, aNi = aR, aNh = aR;
            for (int k = 0; k < HH; k += 32) {
                short8 f0 = ldfrag_l(w0 + k), f1 = ldfrag_l(w1 + k), f2 = ldfrag_l(w2 + k);
                short8 xh = sysld_frag16(ah + k), xl = sysld_frag16(al + k);
                aR = mfma(xh, f0, aR);   aR = mfma(xl, f0, aR);
                aZ = mfma(xh, f1, aZ);   aZ = mfma(xl, f1, aZ);
                aNh = mfma(xh, f2, aNh); aNh = mfma(xl, f2, aNh);
            }
            const ushort_t* ap = poseA + (size_t)(wv * 16 + col) * KP + quad * 8;
            const short* c0 = wih_lds + (size_t)(0  + col) * WIH_PITCH + quad * 8;
            const short* c1 = wih_lds + (size_t)(16 + col) * WIH_PITCH + quad * 8;
            const short* c2 = wih_lds + (size_t)(32 + col) * WIH_PITCH + quad * 8;
            for (int k = 0; k < KP; k += 32) {
                short8 xp = warm_src ? ldfrag(ap + k) : sysld_frag16(ap + k);
                aR = mfma(xp, ldfrag_l(c0 + k), aR);
                aZ = mfma(xp, ldfrag_l(c1 + k), aZ);
                aNi = mfma(xp, ldfrag_l(c2 + k), aNi);
            }
            #pragma unroll
            for (int r = 0; r < 4; ++r) {
                int b = wv * 16 + quad * 4 + r;
                float hold = hFs[(size_t)b * HH + j];
                float rg = sigmoidf(aR[r] + bir);
                float zg = sigmoidf(aZ[r] + biz);
                float ng = tanh_f(aNi[r] + bin + rg * (aNh[r] + bhn));
                float hn = (1.f - zg) * ng + zg * hold;
                hFd[(size_t)b * HH + j] = hn;                 // wg-private across steps
                ushort_t hi = f2bf(hn);
                sysst_u16(&hhid[(size_t)b * HH + j], hi);     // cross-wg -> coherence point
                sysst_u16(&hlod[(size_t)b * HH + j], f2bf(hn - bf2f(hi)));
            }
        }
        { float* tf = hFs; hFs = hFd; hFd = tf; }
        { ushort_t* tp = hhis; hhis = hhid; hhid = tp;
          tp = hlos; hlos = hlod; hlod = tp; }
        btarget += NWG;
        gbar(bar, btarget);
        if (!dec) continue;

        // ======== phase B: scores + softmax + ctx/wctx + pose (wg = batch) ========
        {
            const int b = wg;
            // h = hi + lo (system loads; 8B per array per thread)
            {
                union { unsigned long long u; ushort_t e[4]; } h4, l4;
                h4.u = sysld_u64(hhis + (size_t)b * HH + tid * 4);
                l4.u = sysld_u64(hlos + (size_t)b * HH + tid * 4);
                #pragma unroll
                for (int i = 0; i < 4; ++i)
                    cx[tid * 4 + i] = bf2f(h4.e[i]) + bf2f(l4.e[i]);
            }
            __syncthreads();
            // hoist this lane's h-slice (fixed across all 192 rows)
            float hreg[16];
            #pragma unroll
            for (int i = 0; i < 16; ++i) hreg[i] = cx[lane * 16 + i];
            for (int idx = wv; idx < 192; idx += 4) {
                const ushort_t* rp = (idx < 128)
                    ? (encP + ((size_t)(idx * BB + b) << 10))
                    : (wordP + ((size_t)((idx - 128) * BB + b) << 10));
                short8 v0 = ldfrag(rp + lane * 16);
                short8 v1 = ldfrag(rp + lane * 16 + 8);
                float s = 0.f;
                #pragma unroll
                for (int i = 0; i < 8; ++i) s += bf2f((ushort_t)v0[i]) * hreg[i];
                #pragma unroll
                for (int i = 0; i < 8; ++i) s += bf2f((ushort_t)v1[i]) * hreg[8 + i];
                #pragma unroll
                for (int m = 1; m < 64; m <<= 1) s += __shfl_xor(s, m);
                if (lane == 0) sc[idx] = s;
            }
            __syncthreads();
            if (wv == 0) {
                float a = sc[lane], c = sc[lane + 64];
                float mx = fmaxf(a, c);
                #pragma unroll
                for (int m = 1; m < 64; m <<= 1) mx = fmaxf(mx, __shfl_xor(mx, m));
                float e0 = __expf(a - mx), e1 = __expf(c - mx);
                float sm = e0 + e1;
                #pragma unroll
                for (int m = 1; m < 64; m <<= 1) sm += __shfl_xor(sm, m);
                float inv = 1.f / sm;
                wts[lane] = e0 * inv; wts[lane + 64] = e1 * inv;
            } else if (wv == 1) {
                float a = sc[128 + lane];
                float mx = a;
                #pragma unroll
                for (int m = 1; m < 64; m <<= 1) mx = fmaxf(mx, __shfl_xor(mx, m));
                float e0 = __expf(a - mx);
                float sm = e0;
                #pragma unroll
                for (int m = 1; m < 64; m <<= 1) sm += __shfl_xor(sm, m);
                wts[128 + lane] = e0 / sm;
            }
            __syncthreads();
            // ctx: each thread owns 4 contiguous elems (8B vector loads, L2-warm)
            {
                float a0 = 0.f, a1 = 0.f, a2 = 0.f, a3 = 0.f;
                const ushort_t* basep = encP + ((size_t)b << 10) + tid * 4;
                #pragma unroll 8
                for (int s = 0; s < SS; ++s) {
                    float w = wts[s];
                    union { unsigned long long u; ushort_t e[4]; } v;
                    v.u = *(const unsigned long long*)(basep + ((size_t)(s * BB) << 10));
                    a0 += w * bf2f(v.e[0]); a1 += w * bf2f(v.e[1]);
                    a2 += w * bf2f(v.e[2]); a3 += w * bf2f(v.e[3]);
                }
                cx[1024 + tid * 4 + 0] = a0; cx[1024 + tid * 4 + 1] = a1;
                cx[1024 + tid * 4 + 2] = a2; cx[1024 + tid * 4 + 3] = a3;
            }
            // wctx
            {
                float a0 = 0.f, a1 = 0.f, a2 = 0.f, a3 = 0.f;
                const ushort_t* basep = wordP + ((size_t)b << 10) + tid * 4;
                #pragma unroll 8
                for (int s = 0; s < WLW; ++s) {
                    float w = wts[128 + s];
                    union { unsigned long long u; ushort_t e[4]; } v;
                    v.u = *(const unsigned long long*)(basep + ((size_t)(s * BB) << 10));
                    a0 += w * bf2f(v.e[0]); a1 += w * bf2f(v.e[1]);
                    a2 += w * bf2f(v.e[2]); a3 += w * bf2f(v.e[3]);
                }
                cx[2048 + tid * 4 + 0] = a0; cx[2048 + tid * 4 + 1] = a1;
                cx[2048 + tid * 4 + 2] = a2; cx[2048 + tid * 4 + 3] = a3;
            }
            __syncthreads();
            // pose: hoist this lane's 48-elem cx slice, then 6x16B loads per o-row
            float cr[48];
            #pragma unroll
            for (int i = 0; i < 48; ++i) cr[i] = cx[lane * 48 + i];
            int td = t - PLP;
            for (int oo = 0; oo < 36; ++oo) {
                int o = wv * 36 + oo;   // 0..143
                const ushort_t* wr = wout_p + (size_t)o * (3 * HH) + lane * 48;
                float s = 0.f;
                #pragma unroll
                for (int c6 = 0; c6 < 6; ++c6) {
                    short8 w8 = ldfrag(wr + c6 * 8);
                    #pragma unroll
                    for (int i = 0; i < 8; ++i) s += bf2f((ushort_t)w8[i]) * cr[c6 * 8 + i];
                }
                #pragma unroll
                for (int m = 1; m < 64; m <<= 1) s += __shfl_xor(s, m);
                if (lane == 0) {
                    float v = s + ((o < OO) ? ldf(b_out, o, isbf) : 0.f);
                    if (o < OO) {
                        size_t oi = ((size_t)td * BB + b) * OO + o;
                        if (isbf) ((ushort_t*)out)[oi] = f2bf(v);
                        else      ((float*)out)[oi] = v;
                    }
                    if (o < NWG + 80) // o < 144 always true; keep structure simple
                        sysst_u16(&pose_pad[(size_t)b * KP + o], (o < OO) ? f2bf(v) : (ushort_t)0);
                }
            }
        }
        btarget += NWG;
        gbar(bar, btarget);
    }
}

extern "C" void kernel_launch(void* const* d_in, const int* in_sizes, int n_in,
                              void* d_out, int out_size, void* d_ws, size_t ws_size,
                              hipStream_t stream)
{
    (void)in_sizes; (void)n_in; (void)out_size; (void)ws_size;
    const void* enc_states = d_in[0];
    const void* enc_hidden = d_in[1];
    const void* prev_poses = d_in[2];
    const void* words      = d_in[3];
    const void* W_ed  = d_in[5];
    const void* b_ed  = d_in[6];
    const void* W_att = d_in[7];
    const void* b_att = d_in[8];
    const void* W_watt = d_in[9];
    const void* b_watt = d_in[10];
    const void* W_ih  = d_in[11];
    const void* W_hh  = d_in[12];
    const void* b_ih  = d_in[13];
    const void* b_hh  = d_in[14];
    const void* W_out = d_in[15];
    const void* b_out = d_in[16];

    char* base = (char*)d_ws;
    size_t off = 0;
    auto alloc = [&](size_t bytes) -> char* {
        char* p = base + off;
        off = (off + bytes + 255) & ~(size_t)255;
        return p;
    };
    unsigned* flagbar  = (unsigned*)alloc(512);
    ushort_t* ehcat    = (ushort_t*)alloc((size_t)BB * EE * 2);
    ushort_t* wih_p    = (ushort_t*)alloc((size_t)3 * HH * KP * 2);
    ushort_t* wout_p   = (ushort_t*)alloc((size_t)144 * 3 * HH * 2);
    ushort_t* pp_pad   = (ushort_t*)alloc((size_t)PLP * BB * KP * 2);
    ushort_t* pose_pad = (ushort_t*)alloc((size_t)BB * KP * 2);
    ushort_t* whh_bf   = (ushort_t*)alloc((size_t)3 * HH * HH * 2);
    float*    hF0      = (float*)alloc((size_t)BB * HH * 4);
    float*    hF1      = (float*)alloc((size_t)BB * HH * 4);
    ushort_t* hhi0     = (ushort_t*)alloc((size_t)BB * HH * 2);
    ushort_t* hhi1     = (ushort_t*)alloc((size_t)BB * HH * 2);
    ushort_t* hlo0     = (ushort_t*)alloc((size_t)BB * HH * 2);
    ushort_t* hlo1     = (ushort_t*)alloc((size_t)BB * HH * 2);
    ushort_t* encP     = (ushort_t*)alloc((size_t)SS * BB * HH * 2);
    ushort_t* wordP    = (ushort_t*)alloc((size_t)WLW * BB * HH * 2);

    k_detect<<<1, 256, 0, stream>>>((const unsigned*)enc_states, flagbar);

    k_prep<<<17512, 256, 0, stream>>>(enc_hidden, W_ih, W_out, prev_poses, W_hh,
                                      ehcat, wih_p, wout_p, pp_pad, pose_pad, whh_bf,
                                      flagbar);

    // h0 = ehcat @ W_ed^T + b_ed
    k_gemm<<<16, 256, 0, stream>>>(ehcat, 1, EE, EE, W_ed, 0, EE, EE, b_ed,
                                   hF0, nullptr, hhi0, hlo0, HH, BB, HH, EE, flagbar);
    // encP = enc @ W_att^T + b_att
    k_gemm<<<2048, 256, 0, stream>>>(enc_states, 0, EE, EE, W_att, 0, EE, EE, b_att,
                                     nullptr, encP, nullptr, nullptr, HH, SS * BB, HH, EE, flagbar);
    // wordP = words @ W_watt^T + b_watt
    k_gemm<<<1024, 256, 0, stream>>>(words, 0, 200, 200, W_watt, 0, 200, 200, b_watt,
                                     nullptr, wordP, nullptr, nullptr, HH, WLW * BB, HH, 224, flagbar);

    (void)hipFuncSetAttribute((const void*)k_persist,
                              hipFuncAttributeMaxDynamicSharedMemorySize, 129024);
    k_persist<<<NWG, 256, 129024, stream>>>(encP, wordP, whh_bf, wih_p,
                                            b_ih, b_hh, wout_p, b_out, pp_pad, pose_pad,
                                            hF0, hF1, hhi0, hhi1, hlo0, hlo1,
                                            d_out, flagbar);
}